// Round 2
// baseline (1078.307 us; speedup 1.0000x reference)
//
#include <hip/hip_runtime.h>
#include <math.h>

// Problem constants
#define NN 100000
#define EE 1600000
#define FIN 128
#define HCH 128     // H*C for gat1
#define CCH 32      // C
#define NCLONE 19
#define NTYPE 29
#define ETOT (EE + NN)
#define SCAN_B 49   // ceil(NN / 2048)

typedef __bf16 bf16_t;
typedef bf16_t bf16x2 __attribute__((ext_vector_type(2)));
typedef bf16_t bf16x8 __attribute__((ext_vector_type(8)));
typedef float f32x4 __attribute__((ext_vector_type(4)));

// ---------------------------------------------------------------- conversions
__global__ __launch_bounds__(256) void k_cvt(const float* __restrict__ x,
                                             bf16_t* __restrict__ xb) {
    size_t base = ((size_t)blockIdx.x * 256 + threadIdx.x) * 8;
    if (base >= (size_t)NN * FIN) return;
    float4 f0 = *(const float4*)(x + base);
    float4 f1 = *(const float4*)(x + base + 4);
    bf16x8 v;
    v[0] = (bf16_t)f0.x; v[1] = (bf16_t)f0.y; v[2] = (bf16_t)f0.z; v[3] = (bf16_t)f0.w;
    v[4] = (bf16_t)f1.x; v[5] = (bf16_t)f1.y; v[6] = (bf16_t)f1.z; v[7] = (bf16_t)f1.w;
    *(bf16x8*)(xb + base) = v;
}

// Build transposed bf16 weight blobs: WbT[n][k] (384x128), Wb2T[n][k] (64x128)
__global__ __launch_bounds__(256) void k_wcvt(const float* __restrict__ Wl1,
                                              const float* __restrict__ Wr1,
                                              const float* __restrict__ Ws,
                                              const float* __restrict__ Wl2,
                                              const float* __restrict__ Wr2,
                                              bf16_t* __restrict__ WbT,
                                              bf16_t* __restrict__ Wb2T) {
    int t = blockIdx.x * 256 + threadIdx.x;
    if (t < 384 * 128) {
        int n = t >> 7, k = t & 127;
        const float* W = (n < 128) ? Wl1 : ((n < 256) ? Wr1 : Ws);
        WbT[t] = (bf16_t)W[k * 128 + (n & 127)];
    } else if (t < 384 * 128 + 64 * 128) {
        int u = t - 384 * 128;
        int n = u >> 7, k = u & 127;
        const float* W = (n < 32) ? Wl2 : Wr2;
        Wb2T[u] = (bf16_t)W[k * 32 + (n & 31)];
    }
}

// ---------------------------------------------------------------- degree + attr sum
__global__ __launch_bounds__(256) void k_deg(const int* __restrict__ ei,
                                             const float* __restrict__ ea,
                                             int* __restrict__ deg,
                                             float* __restrict__ asum) {
    int e = blockIdx.x * 256 + threadIdx.x;
    if (e < EE) {
        int d = ei[EE + e];
        atomicAdd(&deg[d], 1);
        atomicAdd(&asum[d], ea[e]);
    }
}

__global__ __launch_bounds__(256) void k_mean(const int* __restrict__ deg,
                                              const float* __restrict__ asum,
                                              float* __restrict__ mattr) {
    int v = blockIdx.x * 256 + threadIdx.x;
    if (v < NN) mattr[v] = asum[v] / fmaxf((float)deg[v], 1.0f);
}

// ---------------------------------------------------------------- exclusive scan of deg
__global__ __launch_bounds__(256) void k_scan1(const int* __restrict__ deg,
                                               int* __restrict__ offs,
                                               int* __restrict__ bsum) {
    __shared__ int tsum[256];
    int b = blockIdx.x, tid = threadIdx.x;
    int base = b * 2048;
    int loc[8];
    int s = 0;
    #pragma unroll
    for (int i = 0; i < 8; ++i) {
        int idx = base + tid * 8 + i;
        int d = (idx < NN) ? deg[idx] : 0;
        loc[i] = s; s += d;
    }
    tsum[tid] = s;
    __syncthreads();
    for (int off = 1; off < 256; off <<= 1) {
        int v = (tid >= off) ? tsum[tid - off] : 0;
        __syncthreads();
        tsum[tid] += v;
        __syncthreads();
    }
    int texcl = tsum[tid] - s;
    #pragma unroll
    for (int i = 0; i < 8; ++i) {
        int idx = base + tid * 8 + i;
        if (idx < NN) offs[idx] = texcl + loc[i];
    }
    if (tid == 255) bsum[b] = tsum[255];
}

__global__ void k_scan2(int* __restrict__ bsum) {
    if (threadIdx.x == 0) {
        int run = 0;
        for (int i = 0; i < SCAN_B; ++i) { int t = bsum[i]; bsum[i] = run; run += t; }
    }
}

__global__ __launch_bounds__(256) void k_scan3(int* __restrict__ offs,
                                               const int* __restrict__ bsum) {
    int i = blockIdx.x * 256 + threadIdx.x;
    if (i < NN) offs[i] += bsum[i >> 11];
}

// ---------------------------------------------------------------- CSR fill (packed edge record)
__global__ __launch_bounds__(256) void k_fill(const int* __restrict__ ei,
                                              const float* __restrict__ ea,
                                              const int* __restrict__ offs,
                                              int* __restrict__ cur,
                                              int4* __restrict__ ep) {
    int e = blockIdx.x * 256 + threadIdx.x;
    if (e < EE) {
        int d = ei[EE + e];
        int pos = offs[d] + atomicAdd(&cur[d], 1);
        ep[pos] = make_int4(ei[e], __float_as_int(ea[e]), e, 0);
    }
}

// ---------------------------------------------------------------- GEMM1 (MFMA): xb @ WbT^T -> [xl1|xr1|skip]
// BM=128, BN=64, K=128. 4 waves (2x2), wave tile 64x32. LDS XOR-swizzled (16B granules).
__global__ __launch_bounds__(256) void k_gemm1(const bf16_t* __restrict__ xb,
                                               const bf16_t* __restrict__ WbT,
                                               bf16_t* __restrict__ xl,
                                               bf16_t* __restrict__ xr,
                                               float* __restrict__ sk) {
    __shared__ bf16_t As[128 * 128];
    __shared__ bf16_t Bs[64 * 128];
    const int tid = threadIdx.x;
    const int row0 = blockIdx.x * 128;
    const int col0 = blockIdx.y * 64;
    #pragma unroll
    for (int i = 0; i < 8; ++i) {
        int c = i * 256 + tid;
        int r = c >> 4, g = c & 15;
        int gr = row0 + r;
        bf16x8 v = {};
        if (gr < NN) v = *(const bf16x8*)(xb + (size_t)gr * 128 + g * 8);
        *(bf16x8*)&As[r * 128 + ((g ^ (r & 7)) * 8)] = v;
    }
    #pragma unroll
    for (int i = 0; i < 4; ++i) {
        int c = i * 256 + tid;
        int n = c >> 4, g = c & 15;
        bf16x8 v = *(const bf16x8*)(WbT + (size_t)(col0 + n) * 128 + g * 8);
        *(bf16x8*)&Bs[n * 128 + ((g ^ (n & 7)) * 8)] = v;
    }
    __syncthreads();

    const int wid = tid >> 6, lane = tid & 63;
    const int wm = wid >> 1, wn = wid & 1;
    const int lr = lane & 15, lg = lane >> 4;
    f32x4 acc[4][2] = {};
    #pragma unroll
    for (int ks = 0; ks < 4; ++ks) {
        int g = ks * 4 + lg;
        bf16x8 b0, b1;
        {
            int n = wn * 32 + lr;
            b0 = *(const bf16x8*)&Bs[n * 128 + ((g ^ (n & 7)) * 8)];
            n += 16;
            b1 = *(const bf16x8*)&Bs[n * 128 + ((g ^ (n & 7)) * 8)];
        }
        #pragma unroll
        for (int mi = 0; mi < 4; ++mi) {
            int r = wm * 64 + mi * 16 + lr;
            bf16x8 a = *(const bf16x8*)&As[r * 128 + ((g ^ (r & 7)) * 8)];
            acc[mi][0] = __builtin_amdgcn_mfma_f32_16x16x32_bf16(a, b0, acc[mi][0], 0, 0, 0);
            acc[mi][1] = __builtin_amdgcn_mfma_f32_16x16x32_bf16(a, b1, acc[mi][1], 0, 0, 0);
        }
    }
    #pragma unroll
    for (int mi = 0; mi < 4; ++mi)
        #pragma unroll
        for (int ni = 0; ni < 2; ++ni)
            #pragma unroll
            for (int j = 0; j < 4; ++j) {
                int gr = row0 + wm * 64 + mi * 16 + lg * 4 + j;
                if (gr >= NN) continue;
                int n = col0 + wn * 32 + ni * 16 + lr;
                float val = acc[mi][ni][j];
                if (n < 128) xl[(size_t)gr * 128 + n] = (bf16_t)val;
                else if (n < 256) xr[(size_t)gr * 128 + (n - 128)] = (bf16_t)val;
                else sk[(size_t)gr * 128 + (n - 256)] = val;
            }
}

// ---------------------------------------------------------------- GAT1: one wave per dst node, online softmax
__global__ __launch_bounds__(256) void k_gat1(const bf16_t* __restrict__ xl1,
                                              const bf16_t* __restrict__ xr1,
                                              const float* __restrict__ mattr,
                                              const int* __restrict__ offs,
                                              const int* __restrict__ deg,
                                              const int4* __restrict__ ep,
                                              const float* __restrict__ att1,
                                              const float* __restrict__ we1,
                                              const float* __restrict__ b1,
                                              const float* __restrict__ skipb,
                                              float* __restrict__ hio) {
    int v = (blockIdx.x * 256 + threadIdx.x) >> 6;
    if (v >= NN) return;
    int l = threadIdx.x & 63;
    int c0 = l * 2;
    bf16x2 xrv = *(const bf16x2*)(xr1 + (size_t)v * 128 + c0);
    float xra = (float)xrv[0], xrb = (float)xrv[1];
    float2 at = *(const float2*)(att1 + c0);
    float2 we = *(const float2*)(we1 + c0);
    // self loop first
    bf16x2 sv = *(const bf16x2*)(xl1 + (size_t)v * 128 + c0);
    float xs0 = (float)sv[0], xs1 = (float)sv[1];
    float eav = mattr[v];
    float m0 = xs0 + xra + eav * we.x; m0 = (m0 > 0.f) ? m0 : 0.2f * m0;
    float m1 = xs1 + xrb + eav * we.y; m1 = (m1 > 0.f) ? m1 : 0.2f * m1;
    float p = m0 * at.x + m1 * at.y;
    p += __shfl_xor(p, 1, 16);
    p += __shfl_xor(p, 2, 16);
    p += __shfl_xor(p, 4, 16);
    p += __shfl_xor(p, 8, 16);
    float mr = p, den = 1.f, n0 = xs0, n1 = xs1;
    int st = offs[v], dg = deg[v];
    int i = 0;
    for (; i + 2 <= dg; i += 2) {
        int4 e0 = ep[st + i];
        int4 e1 = ep[st + i + 1];
        bf16x2 a0 = *(const bf16x2*)(xl1 + (size_t)e0.x * 128 + c0);
        bf16x2 a1 = *(const bf16x2*)(xl1 + (size_t)e1.x * 128 + c0);
        float ea0 = __int_as_float(e0.y), ea1 = __int_as_float(e1.y);
        float x00 = (float)a0[0], x01 = (float)a0[1];
        float x10 = (float)a1[0], x11 = (float)a1[1];
        float q0, q1;
        {
            float u0 = x00 + xra + ea0 * we.x; u0 = (u0 > 0.f) ? u0 : 0.2f * u0;
            float u1 = x01 + xrb + ea0 * we.y; u1 = (u1 > 0.f) ? u1 : 0.2f * u1;
            q0 = u0 * at.x + u1 * at.y;
            float w0 = x10 + xra + ea1 * we.x; w0 = (w0 > 0.f) ? w0 : 0.2f * w0;
            float w1 = x11 + xrb + ea1 * we.y; w1 = (w1 > 0.f) ? w1 : 0.2f * w1;
            q1 = w0 * at.x + w1 * at.y;
        }
        q0 += __shfl_xor(q0, 1, 16);  q1 += __shfl_xor(q1, 1, 16);
        q0 += __shfl_xor(q0, 2, 16);  q1 += __shfl_xor(q1, 2, 16);
        q0 += __shfl_xor(q0, 4, 16);  q1 += __shfl_xor(q1, 4, 16);
        q0 += __shfl_xor(q0, 8, 16);  q1 += __shfl_xor(q1, 8, 16);
        {
            float nm = fmaxf(mr, q0);
            float sc = __expf(mr - nm);
            float ex = __expf(q0 - nm);
            den = den * sc + ex; n0 = n0 * sc + ex * x00; n1 = n1 * sc + ex * x01; mr = nm;
        }
        {
            float nm = fmaxf(mr, q1);
            float sc = __expf(mr - nm);
            float ex = __expf(q1 - nm);
            den = den * sc + ex; n0 = n0 * sc + ex * x10; n1 = n1 * sc + ex * x11; mr = nm;
        }
    }
    if (i < dg) {
        int4 e0 = ep[st + i];
        bf16x2 a0 = *(const bf16x2*)(xl1 + (size_t)e0.x * 128 + c0);
        float ea0 = __int_as_float(e0.y);
        float x00 = (float)a0[0], x01 = (float)a0[1];
        float u0 = x00 + xra + ea0 * we.x; u0 = (u0 > 0.f) ? u0 : 0.2f * u0;
        float u1 = x01 + xrb + ea0 * we.y; u1 = (u1 > 0.f) ? u1 : 0.2f * u1;
        float q0 = u0 * at.x + u1 * at.y;
        q0 += __shfl_xor(q0, 1, 16);
        q0 += __shfl_xor(q0, 2, 16);
        q0 += __shfl_xor(q0, 4, 16);
        q0 += __shfl_xor(q0, 8, 16);
        float nm = fmaxf(mr, q0);
        float sc = __expf(mr - nm);
        float ex = __expf(q0 - nm);
        den = den * sc + ex; n0 = n0 * sc + ex * x00; n1 = n1 * sc + ex * x01; mr = nm;
    }
    float inv = 1.0f / (den + 1e-16f);
    size_t o = (size_t)v * 128 + c0;
    float2 skv = *(const float2*)(hio + o);
    float2 bb = *(const float2*)(b1 + c0);
    float2 sb = *(const float2*)(skipb + c0);
    float2 res;
    res.x = n0 * inv + bb.x + skv.x + sb.x;
    res.y = n1 * inv + bb.y + skv.y + sb.y;
    *(float2*)(hio + o) = res;
}

// ---------------------------------------------------------------- batchnorm stats (vectorized)
__global__ __launch_bounds__(256) void k_bnstats(const float* __restrict__ h,
                                                 float* __restrict__ bns,
                                                 float* __restrict__ bnq) {
    int tid = blockIdx.x * 256 + threadIdx.x;
    int cg = tid & 31;
    int r0 = tid >> 5;
    int stride = (gridDim.x * 256) >> 5;
    float4 s = {0, 0, 0, 0}, q = {0, 0, 0, 0};
    for (int r = r0; r < NN; r += stride) {
        float4 vv = *(const float4*)&h[(size_t)r * 128 + cg * 4];
        s.x += vv.x; s.y += vv.y; s.z += vv.z; s.w += vv.w;
        q.x += vv.x * vv.x; q.y += vv.y * vv.y; q.z += vv.z * vv.z; q.w += vv.w * vv.w;
    }
    atomicAdd(&bns[cg * 4 + 0], s.x); atomicAdd(&bns[cg * 4 + 1], s.y);
    atomicAdd(&bns[cg * 4 + 2], s.z); atomicAdd(&bns[cg * 4 + 3], s.w);
    atomicAdd(&bnq[cg * 4 + 0], q.x); atomicAdd(&bnq[cg * 4 + 1], q.y);
    atomicAdd(&bnq[cg * 4 + 2], q.z); atomicAdd(&bnq[cg * 4 + 3], q.w);
}

__global__ void k_bnfinal(const float* __restrict__ bns, const float* __restrict__ bnq,
                          const float* __restrict__ g, const float* __restrict__ b,
                          float* __restrict__ scale, float* __restrict__ shift) {
    int c = threadIdx.x;
    if (c < 128) {
        float mu = bns[c] * (1.0f / NN);
        float var = bnq[c] * (1.0f / NN) - mu * mu;
        float rs = rsqrtf(var + 1e-5f);
        float a = rs * g[c];
        scale[c] = a;
        shift[c] = b[c] - mu * a;
    }
}

// ---------------------------------------------------------------- GEMM2 (MFMA): elu(bn(h)) @ Wb2T^T -> [xl2 bf16 | xr2 f32]
__global__ __launch_bounds__(256) void k_gemm2(const float* __restrict__ h,
                                               const float* __restrict__ scl,
                                               const float* __restrict__ shf,
                                               const bf16_t* __restrict__ Wb2T,
                                               bf16_t* __restrict__ xl2,
                                               float* __restrict__ xr2) {
    __shared__ bf16_t As[128 * 128];
    __shared__ bf16_t Bs[64 * 128];
    const int tid = threadIdx.x;
    const int row0 = blockIdx.x * 128;
    #pragma unroll
    for (int i = 0; i < 8; ++i) {
        int c = i * 256 + tid;
        int r = c >> 4, g = c & 15;
        int gr = row0 + r;
        bf16x8 v = {};
        if (gr < NN) {
            float4 f0 = *(const float4*)(h + (size_t)gr * 128 + g * 8);
            float4 f1 = *(const float4*)(h + (size_t)gr * 128 + g * 8 + 4);
            float4 s0 = *(const float4*)(scl + g * 8);
            float4 s1 = *(const float4*)(scl + g * 8 + 4);
            float4 t0 = *(const float4*)(shf + g * 8);
            float4 t1 = *(const float4*)(shf + g * 8 + 4);
            float e[8];
            e[0] = f0.x * s0.x + t0.x; e[1] = f0.y * s0.y + t0.y;
            e[2] = f0.z * s0.z + t0.z; e[3] = f0.w * s0.w + t0.w;
            e[4] = f1.x * s1.x + t1.x; e[5] = f1.y * s1.y + t1.y;
            e[6] = f1.z * s1.z + t1.z; e[7] = f1.w * s1.w + t1.w;
            #pragma unroll
            for (int j = 0; j < 8; ++j) {
                float vv = e[j];
                vv = (vv > 0.f) ? vv : (__expf(vv) - 1.0f);
                v[j] = (bf16_t)vv;
            }
        }
        *(bf16x8*)&As[r * 128 + ((g ^ (r & 7)) * 8)] = v;
    }
    #pragma unroll
    for (int i = 0; i < 4; ++i) {
        int c = i * 256 + tid;
        int n = c >> 4, g = c & 15;
        bf16x8 v = *(const bf16x8*)(Wb2T + (size_t)n * 128 + g * 8);
        *(bf16x8*)&Bs[n * 128 + ((g ^ (n & 7)) * 8)] = v;
    }
    __syncthreads();

    const int wid = tid >> 6, lane = tid & 63;
    const int wm = wid >> 1, wn = wid & 1;
    const int lr = lane & 15, lg = lane >> 4;
    f32x4 acc[4][2] = {};
    #pragma unroll
    for (int ks = 0; ks < 4; ++ks) {
        int g = ks * 4 + lg;
        bf16x8 b0, b1;
        {
            int n = wn * 32 + lr;
            b0 = *(const bf16x8*)&Bs[n * 128 + ((g ^ (n & 7)) * 8)];
            n += 16;
            b1 = *(const bf16x8*)&Bs[n * 128 + ((g ^ (n & 7)) * 8)];
        }
        #pragma unroll
        for (int mi = 0; mi < 4; ++mi) {
            int r = wm * 64 + mi * 16 + lr;
            bf16x8 a = *(const bf16x8*)&As[r * 128 + ((g ^ (r & 7)) * 8)];
            acc[mi][0] = __builtin_amdgcn_mfma_f32_16x16x32_bf16(a, b0, acc[mi][0], 0, 0, 0);
            acc[mi][1] = __builtin_amdgcn_mfma_f32_16x16x32_bf16(a, b1, acc[mi][1], 0, 0, 0);
        }
    }
    #pragma unroll
    for (int mi = 0; mi < 4; ++mi)
        #pragma unroll
        for (int ni = 0; ni < 2; ++ni)
            #pragma unroll
            for (int j = 0; j < 4; ++j) {
                int gr = row0 + wm * 64 + mi * 16 + lg * 4 + j;
                if (gr >= NN) continue;
                int n = wn * 32 + ni * 16 + lr;
                float val = acc[mi][ni][j];
                if (n < 32) xl2[(size_t)gr * 32 + n] = (bf16_t)val;
                else xr2[(size_t)gr * 32 + (n - 32)] = val;
            }
}

// ---------------------------------------------------------------- GAT2: 32-lane group per node
__global__ __launch_bounds__(256) void k_gat2(const bf16_t* __restrict__ xl2,
                                              const float* __restrict__ xr2,
                                              const float* __restrict__ mattr,
                                              const int* __restrict__ offs,
                                              const int* __restrict__ deg,
                                              const int4* __restrict__ ep,
                                              const float* __restrict__ att2,
                                              const float* __restrict__ we2,
                                              const float* __restrict__ b2,
                                              float* __restrict__ h3,
                                              float* __restrict__ wout,
                                              float* __restrict__ Mf,
                                              float* __restrict__ Dn) {
    int v = (blockIdx.x * 256 + threadIdx.x) >> 5;
    if (v >= NN) return;
    int l = threadIdx.x & 31;
    float xr = xr2[(size_t)v * 32 + l];
    float at = att2[l];
    float we = we2[l];
    // self loop
    float xs = (float)xl2[(size_t)v * 32 + l];
    float eav = mattr[v];
    float m = xs + xr + eav * we;
    m = (m > 0.f) ? m : 0.2f * m;
    float p = m * at;
    p += __shfl_xor(p, 1, 32);
    p += __shfl_xor(p, 2, 32);
    p += __shfl_xor(p, 4, 32);
    p += __shfl_xor(p, 8, 32);
    p += __shfl_xor(p, 16, 32);
    if (l == 0) wout[EE + v] = p;
    float mr = p, den = 1.f, num = xs;
    int st = offs[v], dg = deg[v];
    int i = 0;
    for (; i + 2 <= dg; i += 2) {
        int4 e0 = ep[st + i];
        int4 e1 = ep[st + i + 1];
        float x0 = (float)xl2[(size_t)e0.x * 32 + l];
        float x1 = (float)xl2[(size_t)e1.x * 32 + l];
        float u0 = x0 + xr + __int_as_float(e0.y) * we; u0 = (u0 > 0.f) ? u0 : 0.2f * u0;
        float u1 = x1 + xr + __int_as_float(e1.y) * we; u1 = (u1 > 0.f) ? u1 : 0.2f * u1;
        float q0 = u0 * at, q1 = u1 * at;
        q0 += __shfl_xor(q0, 1, 32);  q1 += __shfl_xor(q1, 1, 32);
        q0 += __shfl_xor(q0, 2, 32);  q1 += __shfl_xor(q1, 2, 32);
        q0 += __shfl_xor(q0, 4, 32);  q1 += __shfl_xor(q1, 4, 32);
        q0 += __shfl_xor(q0, 8, 32);  q1 += __shfl_xor(q1, 8, 32);
        q0 += __shfl_xor(q0, 16, 32); q1 += __shfl_xor(q1, 16, 32);
        if (l == 0) { wout[e0.z] = q0; wout[e1.z] = q1; }
        {
            float nm = fmaxf(mr, q0);
            float sc = __expf(mr - nm);
            float ex = __expf(q0 - nm);
            den = den * sc + ex; num = num * sc + ex * x0; mr = nm;
        }
        {
            float nm = fmaxf(mr, q1);
            float sc = __expf(mr - nm);
            float ex = __expf(q1 - nm);
            den = den * sc + ex; num = num * sc + ex * x1; mr = nm;
        }
    }
    if (i < dg) {
        int4 e0 = ep[st + i];
        float x0 = (float)xl2[(size_t)e0.x * 32 + l];
        float u0 = x0 + xr + __int_as_float(e0.y) * we; u0 = (u0 > 0.f) ? u0 : 0.2f * u0;
        float q0 = u0 * at;
        q0 += __shfl_xor(q0, 1, 32);
        q0 += __shfl_xor(q0, 2, 32);
        q0 += __shfl_xor(q0, 4, 32);
        q0 += __shfl_xor(q0, 8, 32);
        q0 += __shfl_xor(q0, 16, 32);
        if (l == 0) wout[e0.z] = q0;
        float nm = fmaxf(mr, q0);
        float sc = __expf(mr - nm);
        float ex = __expf(q0 - nm);
        den = den * sc + ex; num = num * sc + ex * x0; mr = nm;
    }
    if (l == 0) { Mf[v] = mr; Dn[v] = den; }
    float o = num / (den + 1e-16f) + b2[l];
    h3[(size_t)v * 32 + l] = (o > 0.f) ? o : (__expf(o) - 1.0f);
}

// ---------------------------------------------------------------- finalize attention weights w
__global__ __launch_bounds__(256) void k_wfinal(const int* __restrict__ ei,
                                                const float* __restrict__ Mf,
                                                const float* __restrict__ Dn,
                                                float* __restrict__ wout) {
    int e = blockIdx.x * 256 + threadIdx.x;
    if (e >= ETOT) return;
    int d = (e < EE) ? ei[EE + e] : (e - EE);
    float al = wout[e];
    wout[e] = __expf(al - Mf[d]) / (Dn[d] + 1e-16f);
}

// ---------------------------------------------------------------- heads
__global__ __launch_bounds__(256) void k_head(const float* __restrict__ h3,
                                              const float* __restrict__ fc1W,
                                              const float* __restrict__ fc1b,
                                              const float* __restrict__ Wc,
                                              const float* __restrict__ bc,
                                              const float* __restrict__ Wt,
                                              const float* __restrict__ bt,
                                              float* __restrict__ outp) {
    __shared__ float sW1[32 * 32];
    __shared__ float sWc[32 * NCLONE];
    __shared__ float sWt[32 * NTYPE];
    __shared__ float sb1[32], sbc[NCLONE], sbt[NTYPE];
    int tid = threadIdx.x;
    for (int i = tid; i < 1024; i += 256) sW1[i] = fc1W[i];
    for (int i = tid; i < 32 * NCLONE; i += 256) sWc[i] = Wc[i];
    for (int i = tid; i < 32 * NTYPE; i += 256) sWt[i] = Wt[i];
    if (tid < 32) sb1[tid] = fc1b[tid];
    if (tid < NCLONE) sbc[tid] = bc[tid];
    if (tid < NTYPE) sbt[tid] = bt[tid];
    __syncthreads();
    int g = tid >> 5, l = tid & 31;
    int v = blockIdx.x * 8 + g;
    if (v >= NN) return;
    float x = h3[(size_t)v * CCH + l];
    float acc = sb1[l];
    #pragma unroll
    for (int c = 0; c < 32; ++c) {
        float xc = __shfl(x, c, 32);
        acc += xc * sW1[c * 32 + l];
    }
    float hl = fmaxf(acc, 0.0f);
    float at = (l < NTYPE) ? sbt[l] : 0.0f;
    float ac = (l < NCLONE) ? sbc[l] : 0.0f;
    #pragma unroll
    for (int c = 0; c < 32; ++c) {
        float hc = __shfl(hl, c, 32);
        float wt_ = (l < NTYPE) ? sWt[c * NTYPE + l] : 0.0f;
        float wc_ = (l < NCLONE) ? sWc[c * NCLONE + l] : 0.0f;
        at += hc * wt_;
        ac += hc * wc_;
    }
    float vt = (l < NTYPE) ? at : -INFINITY;
    float mt = vt;
    mt = fmaxf(mt, __shfl_xor(mt, 16, 32));
    mt = fmaxf(mt, __shfl_xor(mt, 8, 32));
    mt = fmaxf(mt, __shfl_xor(mt, 4, 32));
    mt = fmaxf(mt, __shfl_xor(mt, 2, 32));
    mt = fmaxf(mt, __shfl_xor(mt, 1, 32));
    float et = __expf(vt - mt);
    float stt = et;
    stt += __shfl_xor(stt, 16, 32);
    stt += __shfl_xor(stt, 8, 32);
    stt += __shfl_xor(stt, 4, 32);
    stt += __shfl_xor(stt, 2, 32);
    stt += __shfl_xor(stt, 1, 32);
    float lt = vt - mt - logf(stt);
    float vc = (l < NCLONE) ? ac : -INFINITY;
    float mc = vc;
    mc = fmaxf(mc, __shfl_xor(mc, 16, 32));
    mc = fmaxf(mc, __shfl_xor(mc, 8, 32));
    mc = fmaxf(mc, __shfl_xor(mc, 4, 32));
    mc = fmaxf(mc, __shfl_xor(mc, 2, 32));
    mc = fmaxf(mc, __shfl_xor(mc, 1, 32));
    float ec = __expf(vc - mc);
    float sc = ec;
    sc += __shfl_xor(sc, 16, 32);
    sc += __shfl_xor(sc, 8, 32);
    sc += __shfl_xor(sc, 4, 32);
    sc += __shfl_xor(sc, 2, 32);
    sc += __shfl_xor(sc, 1, 32);
    float lc = vc - mc - logf(sc);
    size_t ob = (size_t)v * 48;
    if (l < NCLONE) outp[ob + l] = lc;
    if (l < NTYPE) outp[ob + NCLONE + l] = lt;
}

// ---------------------------------------------------------------- launcher
extern "C" void kernel_launch(void* const* d_in, const int* in_sizes, int n_in,
                              void* d_out, int out_size, void* d_ws, size_t ws_size,
                              hipStream_t stream) {
    const float* x     = (const float*)d_in[0];
    const int*   ei    = (const int*)d_in[1];
    const float* ea    = (const float*)d_in[2];
    const float* Wl1   = (const float*)d_in[3];
    const float* Wr1   = (const float*)d_in[4];
    const float* We1   = (const float*)d_in[5];
    const float* att1  = (const float*)d_in[6];
    const float* b1    = (const float*)d_in[7];
    const float* skipW = (const float*)d_in[8];
    const float* skipb = (const float*)d_in[9];
    const float* bng   = (const float*)d_in[10];
    const float* bnb   = (const float*)d_in[11];
    const float* Wl2   = (const float*)d_in[12];
    const float* Wr2   = (const float*)d_in[13];
    const float* We2   = (const float*)d_in[14];
    const float* att2  = (const float*)d_in[15];
    const float* b2    = (const float*)d_in[16];
    const float* fc1W  = (const float*)d_in[17];
    const float* fc1b  = (const float*)d_in[18];
    const float* Wc    = (const float*)d_in[19];
    const float* bc    = (const float*)d_in[20];
    const float* Wt    = (const float*)d_in[21];
    const float* bt    = (const float*)d_in[22];
    float* out = (float*)d_out;
    float* wout = out + (size_t)NN * 48;

    const size_t NF = (size_t)NN * FIN;   // 12.8M
    char* w = (char*)d_ws;
    bf16_t* xb   = (bf16_t*)w;  w += NF * 2;
    bf16_t* xl1b = (bf16_t*)w;  w += NF * 2;
    bf16_t* xr1b = (bf16_t*)w;  w += NF * 2;
    float*  hbuf = (float*)w;   w += NF * 4;
    int4*   ep   = (int4*)w;    w += (size_t)EE * 16;
    int* deg   = (int*)w;   w += (size_t)NN * 4;
    int* offs  = (int*)w;   w += (size_t)NN * 4;
    int* cur   = (int*)w;   w += (size_t)NN * 4;
    float* asum  = (float*)w; w += (size_t)NN * 4;
    float* mattr = (float*)w; w += (size_t)NN * 4;
    float* Mf    = (float*)w; w += (size_t)NN * 4;
    float* Dn    = (float*)w; w += (size_t)NN * 4;
    int*   bsum  = (int*)w;   w += 64 * 4;
    float* bns   = (float*)w; w += 128 * 4;
    float* bnq   = (float*)w; w += 128 * 4;
    float* scl   = (float*)w; w += 128 * 4;
    float* shf   = (float*)w; w += 128 * 4;
    bf16_t* WbT  = (bf16_t*)w; w += 384 * 128 * 2;
    bf16_t* Wb2T = (bf16_t*)w; w += 64 * 128 * 2;
    // aliases into dead regions
    bf16_t* xl2b = xb;                                        // 6.4 MB of xb region
    float*  xr2  = (float*)((char*)d_ws + (size_t)NN * 32 * 2); // after xl2b
    float*  h3   = (float*)xl1b;                              // xl1 region

    hipMemsetAsync(deg, 0, (size_t)NN * 4 * sizeof(int), stream);   // deg, offs, cur, asum
    hipMemsetAsync(bns, 0, 256 * sizeof(float), stream);            // bns, bnq

    k_cvt<<<6250, 256, 0, stream>>>(x, xb);
    k_wcvt<<<224, 256, 0, stream>>>(Wl1, Wr1, skipW, Wl2, Wr2, WbT, Wb2T);

    k_deg<<<6250, 256, 0, stream>>>(ei, ea, deg, asum);
    k_mean<<<391, 256, 0, stream>>>(deg, asum, mattr);
    k_scan1<<<SCAN_B, 256, 0, stream>>>(deg, offs, bsum);
    k_scan2<<<1, 64, 0, stream>>>(bsum);
    k_scan3<<<391, 256, 0, stream>>>(offs, bsum);
    k_fill<<<6250, 256, 0, stream>>>(ei, ea, offs, cur, ep);

    k_gemm1<<<dim3(782, 6), 256, 0, stream>>>(xb, WbT, xl1b, xr1b, hbuf);
    k_gat1<<<25000, 256, 0, stream>>>(xl1b, xr1b, mattr, offs, deg, ep,
                                      att1, We1, b1, skipb, hbuf);
    k_bnstats<<<512, 256, 0, stream>>>(hbuf, bns, bnq);
    k_bnfinal<<<1, 128, 0, stream>>>(bns, bnq, bng, bnb, scl, shf);
    k_gemm2<<<782, 256, 0, stream>>>(hbuf, scl, shf, Wb2T, xl2b, xr2);
    k_gat2<<<12500, 256, 0, stream>>>(xl2b, xr2, mattr, offs, deg, ep,
                                      att2, We2, b2, h3, wout, Mf, Dn);
    k_wfinal<<<6641, 256, 0, stream>>>(ei, Mf, Dn, wout);
    k_head<<<12500, 256, 0, stream>>>(h3, fc1W, fc1b, Wc, bc, Wt, bt, out);
}

// Round 3
// 681.615 us; speedup vs baseline: 1.5820x; 1.5820x over previous
//
#include <hip/hip_runtime.h>
#include <math.h>

// Problem constants
#define NN 100000
#define EE 1600000
#define FIN 128
#define HCH 128     // H*C for gat1
#define CCH 32      // C
#define NCLONE 19
#define NTYPE 29
#define ETOT (EE + NN)
#define SCAN_B 49   // ceil(NN / 2048)

typedef __bf16 bf16_t;
typedef bf16_t bf16x2 __attribute__((ext_vector_type(2)));
typedef bf16_t bf16x8 __attribute__((ext_vector_type(8)));
typedef float f32x4 __attribute__((ext_vector_type(4)));

// ---------------------------------------------------------------- conversions
__global__ __launch_bounds__(256) void k_cvt(const float* __restrict__ x,
                                             bf16_t* __restrict__ xb) {
    size_t base = ((size_t)blockIdx.x * 256 + threadIdx.x) * 8;
    if (base >= (size_t)NN * FIN) return;
    float4 f0 = *(const float4*)(x + base);
    float4 f1 = *(const float4*)(x + base + 4);
    bf16x8 v;
    v[0] = (bf16_t)f0.x; v[1] = (bf16_t)f0.y; v[2] = (bf16_t)f0.z; v[3] = (bf16_t)f0.w;
    v[4] = (bf16_t)f1.x; v[5] = (bf16_t)f1.y; v[6] = (bf16_t)f1.z; v[7] = (bf16_t)f1.w;
    *(bf16x8*)(xb + base) = v;
}

// Build transposed bf16 weight blobs: WbT[n][k] (384x128), Wb2T[n][k] (64x128)
__global__ __launch_bounds__(256) void k_wcvt(const float* __restrict__ Wl1,
                                              const float* __restrict__ Wr1,
                                              const float* __restrict__ Ws,
                                              const float* __restrict__ Wl2,
                                              const float* __restrict__ Wr2,
                                              bf16_t* __restrict__ WbT,
                                              bf16_t* __restrict__ Wb2T) {
    int t = blockIdx.x * 256 + threadIdx.x;
    if (t < 384 * 128) {
        int n = t >> 7, k = t & 127;
        const float* W = (n < 128) ? Wl1 : ((n < 256) ? Wr1 : Ws);
        WbT[t] = (bf16_t)W[k * 128 + (n & 127)];
    } else if (t < 384 * 128 + 64 * 128) {
        int u = t - 384 * 128;
        int n = u >> 7, k = u & 127;
        const float* W = (n < 32) ? Wl2 : Wr2;
        Wb2T[u] = (bf16_t)W[k * 32 + (n & 31)];
    }
}

// ---------------------------------------------------------------- degree + attr sum
__global__ __launch_bounds__(256) void k_deg(const int* __restrict__ ei,
                                             const float* __restrict__ ea,
                                             int* __restrict__ deg,
                                             float* __restrict__ asum) {
    int e = blockIdx.x * 256 + threadIdx.x;
    if (e < EE) {
        int d = ei[EE + e];
        atomicAdd(&deg[d], 1);
        atomicAdd(&asum[d], ea[e]);
    }
}

__global__ __launch_bounds__(256) void k_mean(const int* __restrict__ deg,
                                              const float* __restrict__ asum,
                                              float* __restrict__ mattr) {
    int v = blockIdx.x * 256 + threadIdx.x;
    if (v < NN) mattr[v] = asum[v] / fmaxf((float)deg[v], 1.0f);
}

// ---------------------------------------------------------------- exclusive scan of deg
__global__ __launch_bounds__(256) void k_scan1(const int* __restrict__ deg,
                                               int* __restrict__ offs,
                                               int* __restrict__ bsum) {
    __shared__ int tsum[256];
    int b = blockIdx.x, tid = threadIdx.x;
    int base = b * 2048;
    int loc[8];
    int s = 0;
    #pragma unroll
    for (int i = 0; i < 8; ++i) {
        int idx = base + tid * 8 + i;
        int d = (idx < NN) ? deg[idx] : 0;
        loc[i] = s; s += d;
    }
    tsum[tid] = s;
    __syncthreads();
    for (int off = 1; off < 256; off <<= 1) {
        int v = (tid >= off) ? tsum[tid - off] : 0;
        __syncthreads();
        tsum[tid] += v;
        __syncthreads();
    }
    int texcl = tsum[tid] - s;
    #pragma unroll
    for (int i = 0; i < 8; ++i) {
        int idx = base + tid * 8 + i;
        if (idx < NN) offs[idx] = texcl + loc[i];
    }
    if (tid == 255) bsum[b] = tsum[255];
}

__global__ void k_scan2(int* __restrict__ bsum) {
    if (threadIdx.x == 0) {
        int run = 0;
        for (int i = 0; i < SCAN_B; ++i) { int t = bsum[i]; bsum[i] = run; run += t; }
    }
}

__global__ __launch_bounds__(256) void k_scan3(int* __restrict__ offs,
                                               const int* __restrict__ bsum) {
    int i = blockIdx.x * 256 + threadIdx.x;
    if (i < NN) offs[i] += bsum[i >> 11];
}

// ---------------------------------------------------------------- CSR fill (packed edge record)
__global__ __launch_bounds__(256) void k_fill(const int* __restrict__ ei,
                                              const float* __restrict__ ea,
                                              const int* __restrict__ offs,
                                              int* __restrict__ cur,
                                              int4* __restrict__ ep) {
    int e = blockIdx.x * 256 + threadIdx.x;
    if (e < EE) {
        int d = ei[EE + e];
        int pos = offs[d] + atomicAdd(&cur[d], 1);
        ep[pos] = make_int4(ei[e], __float_as_int(ea[e]), e, 0);
    }
}

// ---------------------------------------------------------------- GEMM1 (MFMA): xb @ WbT^T -> [xl1|xr1|skip]
// BM=128, BN=64, K=128. 4 waves (2x2), wave tile 64x32. LDS XOR-swizzled (16B granules).
__global__ __launch_bounds__(256) void k_gemm1(const bf16_t* __restrict__ xb,
                                               const bf16_t* __restrict__ WbT,
                                               bf16_t* __restrict__ xl,
                                               bf16_t* __restrict__ xr,
                                               float* __restrict__ sk) {
    __shared__ bf16_t As[128 * 128];
    __shared__ bf16_t Bs[64 * 128];
    const int tid = threadIdx.x;
    const int row0 = blockIdx.x * 128;
    const int col0 = blockIdx.y * 64;
    #pragma unroll
    for (int i = 0; i < 8; ++i) {
        int c = i * 256 + tid;
        int r = c >> 4, g = c & 15;
        int gr = row0 + r;
        bf16x8 v = {};
        if (gr < NN) v = *(const bf16x8*)(xb + (size_t)gr * 128 + g * 8);
        *(bf16x8*)&As[r * 128 + ((g ^ (r & 7)) * 8)] = v;
    }
    #pragma unroll
    for (int i = 0; i < 4; ++i) {
        int c = i * 256 + tid;
        int n = c >> 4, g = c & 15;
        bf16x8 v = *(const bf16x8*)(WbT + (size_t)(col0 + n) * 128 + g * 8);
        *(bf16x8*)&Bs[n * 128 + ((g ^ (n & 7)) * 8)] = v;
    }
    __syncthreads();

    const int wid = tid >> 6, lane = tid & 63;
    const int wm = wid >> 1, wn = wid & 1;
    const int lr = lane & 15, lg = lane >> 4;
    f32x4 acc[4][2] = {};
    #pragma unroll
    for (int ks = 0; ks < 4; ++ks) {
        int g = ks * 4 + lg;
        bf16x8 b0, b1;
        {
            int n = wn * 32 + lr;
            b0 = *(const bf16x8*)&Bs[n * 128 + ((g ^ (n & 7)) * 8)];
            n += 16;
            b1 = *(const bf16x8*)&Bs[n * 128 + ((g ^ (n & 7)) * 8)];
        }
        #pragma unroll
        for (int mi = 0; mi < 4; ++mi) {
            int r = wm * 64 + mi * 16 + lr;
            bf16x8 a = *(const bf16x8*)&As[r * 128 + ((g ^ (r & 7)) * 8)];
            acc[mi][0] = __builtin_amdgcn_mfma_f32_16x16x32_bf16(a, b0, acc[mi][0], 0, 0, 0);
            acc[mi][1] = __builtin_amdgcn_mfma_f32_16x16x32_bf16(a, b1, acc[mi][1], 0, 0, 0);
        }
    }
    #pragma unroll
    for (int mi = 0; mi < 4; ++mi)
        #pragma unroll
        for (int ni = 0; ni < 2; ++ni)
            #pragma unroll
            for (int j = 0; j < 4; ++j) {
                int gr = row0 + wm * 64 + mi * 16 + lg * 4 + j;
                if (gr >= NN) continue;
                int n = col0 + wn * 32 + ni * 16 + lr;
                float val = acc[mi][ni][j];
                if (n < 128) xl[(size_t)gr * 128 + n] = (bf16_t)val;
                else if (n < 256) xr[(size_t)gr * 128 + (n - 128)] = (bf16_t)val;
                else sk[(size_t)gr * 128 + (n - 256)] = val;
            }
}

// ---------------------------------------------------------------- GAT1: one wave per dst node, online softmax
__global__ __launch_bounds__(256) void k_gat1(const bf16_t* __restrict__ xl1,
                                              const bf16_t* __restrict__ xr1,
                                              const float* __restrict__ mattr,
                                              const int* __restrict__ offs,
                                              const int* __restrict__ deg,
                                              const int4* __restrict__ ep,
                                              const float* __restrict__ att1,
                                              const float* __restrict__ we1,
                                              const float* __restrict__ b1,
                                              const float* __restrict__ skipb,
                                              float* __restrict__ hio) {
    int v = (blockIdx.x * 256 + threadIdx.x) >> 6;
    if (v >= NN) return;
    int l = threadIdx.x & 63;
    int c0 = l * 2;
    bf16x2 xrv = *(const bf16x2*)(xr1 + (size_t)v * 128 + c0);
    float xra = (float)xrv[0], xrb = (float)xrv[1];
    float2 at = *(const float2*)(att1 + c0);
    float2 we = *(const float2*)(we1 + c0);
    // self loop first
    bf16x2 sv = *(const bf16x2*)(xl1 + (size_t)v * 128 + c0);
    float xs0 = (float)sv[0], xs1 = (float)sv[1];
    float eav = mattr[v];
    float m0 = xs0 + xra + eav * we.x; m0 = (m0 > 0.f) ? m0 : 0.2f * m0;
    float m1 = xs1 + xrb + eav * we.y; m1 = (m1 > 0.f) ? m1 : 0.2f * m1;
    float p = m0 * at.x + m1 * at.y;
    p += __shfl_xor(p, 1, 16);
    p += __shfl_xor(p, 2, 16);
    p += __shfl_xor(p, 4, 16);
    p += __shfl_xor(p, 8, 16);
    float mr = p, den = 1.f, n0 = xs0, n1 = xs1;
    int st = offs[v], dg = deg[v];
    int i = 0;
    for (; i + 2 <= dg; i += 2) {
        int4 e0 = ep[st + i];
        int4 e1 = ep[st + i + 1];
        bf16x2 a0 = *(const bf16x2*)(xl1 + (size_t)e0.x * 128 + c0);
        bf16x2 a1 = *(const bf16x2*)(xl1 + (size_t)e1.x * 128 + c0);
        float ea0 = __int_as_float(e0.y), ea1 = __int_as_float(e1.y);
        float x00 = (float)a0[0], x01 = (float)a0[1];
        float x10 = (float)a1[0], x11 = (float)a1[1];
        float q0, q1;
        {
            float u0 = x00 + xra + ea0 * we.x; u0 = (u0 > 0.f) ? u0 : 0.2f * u0;
            float u1 = x01 + xrb + ea0 * we.y; u1 = (u1 > 0.f) ? u1 : 0.2f * u1;
            q0 = u0 * at.x + u1 * at.y;
            float w0 = x10 + xra + ea1 * we.x; w0 = (w0 > 0.f) ? w0 : 0.2f * w0;
            float w1 = x11 + xrb + ea1 * we.y; w1 = (w1 > 0.f) ? w1 : 0.2f * w1;
            q1 = w0 * at.x + w1 * at.y;
        }
        q0 += __shfl_xor(q0, 1, 16);  q1 += __shfl_xor(q1, 1, 16);
        q0 += __shfl_xor(q0, 2, 16);  q1 += __shfl_xor(q1, 2, 16);
        q0 += __shfl_xor(q0, 4, 16);  q1 += __shfl_xor(q1, 4, 16);
        q0 += __shfl_xor(q0, 8, 16);  q1 += __shfl_xor(q1, 8, 16);
        {
            float nm = fmaxf(mr, q0);
            float sc = __expf(mr - nm);
            float ex = __expf(q0 - nm);
            den = den * sc + ex; n0 = n0 * sc + ex * x00; n1 = n1 * sc + ex * x01; mr = nm;
        }
        {
            float nm = fmaxf(mr, q1);
            float sc = __expf(mr - nm);
            float ex = __expf(q1 - nm);
            den = den * sc + ex; n0 = n0 * sc + ex * x10; n1 = n1 * sc + ex * x11; mr = nm;
        }
    }
    if (i < dg) {
        int4 e0 = ep[st + i];
        bf16x2 a0 = *(const bf16x2*)(xl1 + (size_t)e0.x * 128 + c0);
        float ea0 = __int_as_float(e0.y);
        float x00 = (float)a0[0], x01 = (float)a0[1];
        float u0 = x00 + xra + ea0 * we.x; u0 = (u0 > 0.f) ? u0 : 0.2f * u0;
        float u1 = x01 + xrb + ea0 * we.y; u1 = (u1 > 0.f) ? u1 : 0.2f * u1;
        float q0 = u0 * at.x + u1 * at.y;
        q0 += __shfl_xor(q0, 1, 16);
        q0 += __shfl_xor(q0, 2, 16);
        q0 += __shfl_xor(q0, 4, 16);
        q0 += __shfl_xor(q0, 8, 16);
        float nm = fmaxf(mr, q0);
        float sc = __expf(mr - nm);
        float ex = __expf(q0 - nm);
        den = den * sc + ex; n0 = n0 * sc + ex * x00; n1 = n1 * sc + ex * x01; mr = nm;
    }
    float inv = 1.0f / (den + 1e-16f);
    size_t o = (size_t)v * 128 + c0;
    float2 skv = *(const float2*)(hio + o);
    float2 bb = *(const float2*)(b1 + c0);
    float2 sb = *(const float2*)(skipb + c0);
    float2 res;
    res.x = n0 * inv + bb.x + skv.x + sb.x;
    res.y = n1 * inv + bb.y + skv.y + sb.y;
    *(float2*)(hio + o) = res;
}

// ---------------------------------------------------------------- batchnorm stats: per-block LDS reduce, 1 atomic/channel/block
__global__ __launch_bounds__(256) void k_bnstats(const float* __restrict__ h,
                                                 float* __restrict__ bns,
                                                 float* __restrict__ bnq) {
    __shared__ float sS[8 * 128];
    __shared__ float sQ[8 * 128];
    int tid = threadIdx.x;
    int cg = tid & 31;          // channel group: channels cg*4 .. cg*4+3
    int slot = tid >> 5;        // 8 row slots per block
    int r0 = blockIdx.x * 8 + slot;
    int stride = gridDim.x * 8;
    float4 s = {0, 0, 0, 0}, q = {0, 0, 0, 0};
    for (int r = r0; r < NN; r += stride) {
        float4 vv = *(const float4*)&h[(size_t)r * 128 + cg * 4];
        s.x += vv.x; s.y += vv.y; s.z += vv.z; s.w += vv.w;
        q.x += vv.x * vv.x; q.y += vv.y * vv.y; q.z += vv.z * vv.z; q.w += vv.w * vv.w;
    }
    *(float4*)&sS[slot * 128 + cg * 4] = s;
    *(float4*)&sQ[slot * 128 + cg * 4] = q;
    __syncthreads();
    if (tid < 128) {
        float as = 0.f, aq = 0.f;
        #pragma unroll
        for (int k = 0; k < 8; ++k) {
            as += sS[k * 128 + tid];
            aq += sQ[k * 128 + tid];
        }
        atomicAdd(&bns[tid], as);
        atomicAdd(&bnq[tid], aq);
    }
}

__global__ void k_bnfinal(const float* __restrict__ bns, const float* __restrict__ bnq,
                          const float* __restrict__ g, const float* __restrict__ b,
                          float* __restrict__ scale, float* __restrict__ shift) {
    int c = threadIdx.x;
    if (c < 128) {
        float mu = bns[c] * (1.0f / NN);
        float var = bnq[c] * (1.0f / NN) - mu * mu;
        float rs = rsqrtf(var + 1e-5f);
        float a = rs * g[c];
        scale[c] = a;
        shift[c] = b[c] - mu * a;
    }
}

// ---------------------------------------------------------------- GEMM2 (MFMA): elu(bn(h)) @ Wb2T^T -> [xl2 bf16 | xr2 f32]
__global__ __launch_bounds__(256) void k_gemm2(const float* __restrict__ h,
                                               const float* __restrict__ scl,
                                               const float* __restrict__ shf,
                                               const bf16_t* __restrict__ Wb2T,
                                               bf16_t* __restrict__ xl2,
                                               float* __restrict__ xr2) {
    __shared__ bf16_t As[128 * 128];
    __shared__ bf16_t Bs[64 * 128];
    const int tid = threadIdx.x;
    const int row0 = blockIdx.x * 128;
    #pragma unroll
    for (int i = 0; i < 8; ++i) {
        int c = i * 256 + tid;
        int r = c >> 4, g = c & 15;
        int gr = row0 + r;
        bf16x8 v = {};
        if (gr < NN) {
            float4 f0 = *(const float4*)(h + (size_t)gr * 128 + g * 8);
            float4 f1 = *(const float4*)(h + (size_t)gr * 128 + g * 8 + 4);
            float4 s0 = *(const float4*)(scl + g * 8);
            float4 s1 = *(const float4*)(scl + g * 8 + 4);
            float4 t0 = *(const float4*)(shf + g * 8);
            float4 t1 = *(const float4*)(shf + g * 8 + 4);
            float e[8];
            e[0] = f0.x * s0.x + t0.x; e[1] = f0.y * s0.y + t0.y;
            e[2] = f0.z * s0.z + t0.z; e[3] = f0.w * s0.w + t0.w;
            e[4] = f1.x * s1.x + t1.x; e[5] = f1.y * s1.y + t1.y;
            e[6] = f1.z * s1.z + t1.z; e[7] = f1.w * s1.w + t1.w;
            #pragma unroll
            for (int j = 0; j < 8; ++j) {
                float vv = e[j];
                vv = (vv > 0.f) ? vv : (__expf(vv) - 1.0f);
                v[j] = (bf16_t)vv;
            }
        }
        *(bf16x8*)&As[r * 128 + ((g ^ (r & 7)) * 8)] = v;
    }
    #pragma unroll
    for (int i = 0; i < 4; ++i) {
        int c = i * 256 + tid;
        int n = c >> 4, g = c & 15;
        bf16x8 v = *(const bf16x8*)(Wb2T + (size_t)n * 128 + g * 8);
        *(bf16x8*)&Bs[n * 128 + ((g ^ (n & 7)) * 8)] = v;
    }
    __syncthreads();

    const int wid = tid >> 6, lane = tid & 63;
    const int wm = wid >> 1, wn = wid & 1;
    const int lr = lane & 15, lg = lane >> 4;
    f32x4 acc[4][2] = {};
    #pragma unroll
    for (int ks = 0; ks < 4; ++ks) {
        int g = ks * 4 + lg;
        bf16x8 b0, b1;
        {
            int n = wn * 32 + lr;
            b0 = *(const bf16x8*)&Bs[n * 128 + ((g ^ (n & 7)) * 8)];
            n += 16;
            b1 = *(const bf16x8*)&Bs[n * 128 + ((g ^ (n & 7)) * 8)];
        }
        #pragma unroll
        for (int mi = 0; mi < 4; ++mi) {
            int r = wm * 64 + mi * 16 + lr;
            bf16x8 a = *(const bf16x8*)&As[r * 128 + ((g ^ (r & 7)) * 8)];
            acc[mi][0] = __builtin_amdgcn_mfma_f32_16x16x32_bf16(a, b0, acc[mi][0], 0, 0, 0);
            acc[mi][1] = __builtin_amdgcn_mfma_f32_16x16x32_bf16(a, b1, acc[mi][1], 0, 0, 0);
        }
    }
    #pragma unroll
    for (int mi = 0; mi < 4; ++mi)
        #pragma unroll
        for (int ni = 0; ni < 2; ++ni)
            #pragma unroll
            for (int j = 0; j < 4; ++j) {
                int gr = row0 + wm * 64 + mi * 16 + lg * 4 + j;
                if (gr >= NN) continue;
                int n = wn * 32 + ni * 16 + lr;
                float val = acc[mi][ni][j];
                if (n < 32) xl2[(size_t)gr * 32 + n] = (bf16_t)val;
                else xr2[(size_t)gr * 32 + (n - 32)] = val;
            }
}

// ---------------------------------------------------------------- GAT2: 32-lane group per node
__global__ __launch_bounds__(256) void k_gat2(const bf16_t* __restrict__ xl2,
                                              const float* __restrict__ xr2,
                                              const float* __restrict__ mattr,
                                              const int* __restrict__ offs,
                                              const int* __restrict__ deg,
                                              const int4* __restrict__ ep,
                                              const float* __restrict__ att2,
                                              const float* __restrict__ we2,
                                              const float* __restrict__ b2,
                                              float* __restrict__ h3,
                                              float* __restrict__ wout,
                                              float* __restrict__ Mf,
                                              float* __restrict__ Dn) {
    int v = (blockIdx.x * 256 + threadIdx.x) >> 5;
    if (v >= NN) return;
    int l = threadIdx.x & 31;
    float xr = xr2[(size_t)v * 32 + l];
    float at = att2[l];
    float we = we2[l];
    // self loop
    float xs = (float)xl2[(size_t)v * 32 + l];
    float eav = mattr[v];
    float m = xs + xr + eav * we;
    m = (m > 0.f) ? m : 0.2f * m;
    float p = m * at;
    p += __shfl_xor(p, 1, 32);
    p += __shfl_xor(p, 2, 32);
    p += __shfl_xor(p, 4, 32);
    p += __shfl_xor(p, 8, 32);
    p += __shfl_xor(p, 16, 32);
    if (l == 0) wout[EE + v] = p;
    float mr = p, den = 1.f, num = xs;
    int st = offs[v], dg = deg[v];
    int i = 0;
    for (; i + 2 <= dg; i += 2) {
        int4 e0 = ep[st + i];
        int4 e1 = ep[st + i + 1];
        float x0 = (float)xl2[(size_t)e0.x * 32 + l];
        float x1 = (float)xl2[(size_t)e1.x * 32 + l];
        float u0 = x0 + xr + __int_as_float(e0.y) * we; u0 = (u0 > 0.f) ? u0 : 0.2f * u0;
        float u1 = x1 + xr + __int_as_float(e1.y) * we; u1 = (u1 > 0.f) ? u1 : 0.2f * u1;
        float q0 = u0 * at, q1 = u1 * at;
        q0 += __shfl_xor(q0, 1, 32);  q1 += __shfl_xor(q1, 1, 32);
        q0 += __shfl_xor(q0, 2, 32);  q1 += __shfl_xor(q1, 2, 32);
        q0 += __shfl_xor(q0, 4, 32);  q1 += __shfl_xor(q1, 4, 32);
        q0 += __shfl_xor(q0, 8, 32);  q1 += __shfl_xor(q1, 8, 32);
        q0 += __shfl_xor(q0, 16, 32); q1 += __shfl_xor(q1, 16, 32);
        if (l == 0) { wout[e0.z] = q0; wout[e1.z] = q1; }
        {
            float nm = fmaxf(mr, q0);
            float sc = __expf(mr - nm);
            float ex = __expf(q0 - nm);
            den = den * sc + ex; num = num * sc + ex * x0; mr = nm;
        }
        {
            float nm = fmaxf(mr, q1);
            float sc = __expf(mr - nm);
            float ex = __expf(q1 - nm);
            den = den * sc + ex; num = num * sc + ex * x1; mr = nm;
        }
    }
    if (i < dg) {
        int4 e0 = ep[st + i];
        float x0 = (float)xl2[(size_t)e0.x * 32 + l];
        float u0 = x0 + xr + __int_as_float(e0.y) * we; u0 = (u0 > 0.f) ? u0 : 0.2f * u0;
        float q0 = u0 * at;
        q0 += __shfl_xor(q0, 1, 32);
        q0 += __shfl_xor(q0, 2, 32);
        q0 += __shfl_xor(q0, 4, 32);
        q0 += __shfl_xor(q0, 8, 32);
        q0 += __shfl_xor(q0, 16, 32);
        if (l == 0) wout[e0.z] = q0;
        float nm = fmaxf(mr, q0);
        float sc = __expf(mr - nm);
        float ex = __expf(q0 - nm);
        den = den * sc + ex; num = num * sc + ex * x0; mr = nm;
    }
    if (l == 0) { Mf[v] = mr; Dn[v] = den; }
    float o = num / (den + 1e-16f) + b2[l];
    h3[(size_t)v * 32 + l] = (o > 0.f) ? o : (__expf(o) - 1.0f);
}

// ---------------------------------------------------------------- finalize attention weights w
__global__ __launch_bounds__(256) void k_wfinal(const int* __restrict__ ei,
                                                const float* __restrict__ Mf,
                                                const float* __restrict__ Dn,
                                                float* __restrict__ wout) {
    int e = blockIdx.x * 256 + threadIdx.x;
    if (e >= ETOT) return;
    int d = (e < EE) ? ei[EE + e] : (e - EE);
    float al = wout[e];
    wout[e] = __expf(al - Mf[d]) / (Dn[d] + 1e-16f);
}

// ---------------------------------------------------------------- heads
__global__ __launch_bounds__(256) void k_head(const float* __restrict__ h3,
                                              const float* __restrict__ fc1W,
                                              const float* __restrict__ fc1b,
                                              const float* __restrict__ Wc,
                                              const float* __restrict__ bc,
                                              const float* __restrict__ Wt,
                                              const float* __restrict__ bt,
                                              float* __restrict__ outp) {
    __shared__ float sW1[32 * 32];
    __shared__ float sWc[32 * NCLONE];
    __shared__ float sWt[32 * NTYPE];
    __shared__ float sb1[32], sbc[NCLONE], sbt[NTYPE];
    int tid = threadIdx.x;
    for (int i = tid; i < 1024; i += 256) sW1[i] = fc1W[i];
    for (int i = tid; i < 32 * NCLONE; i += 256) sWc[i] = Wc[i];
    for (int i = tid; i < 32 * NTYPE; i += 256) sWt[i] = Wt[i];
    if (tid < 32) sb1[tid] = fc1b[tid];
    if (tid < NCLONE) sbc[tid] = bc[tid];
    if (tid < NTYPE) sbt[tid] = bt[tid];
    __syncthreads();
    int g = tid >> 5, l = tid & 31;
    int v = blockIdx.x * 8 + g;
    if (v >= NN) return;
    float x = h3[(size_t)v * CCH + l];
    float acc = sb1[l];
    #pragma unroll
    for (int c = 0; c < 32; ++c) {
        float xc = __shfl(x, c, 32);
        acc += xc * sW1[c * 32 + l];
    }
    float hl = fmaxf(acc, 0.0f);
    float at = (l < NTYPE) ? sbt[l] : 0.0f;
    float ac = (l < NCLONE) ? sbc[l] : 0.0f;
    #pragma unroll
    for (int c = 0; c < 32; ++c) {
        float hc = __shfl(hl, c, 32);
        float wt_ = (l < NTYPE) ? sWt[c * NTYPE + l] : 0.0f;
        float wc_ = (l < NCLONE) ? sWc[c * NCLONE + l] : 0.0f;
        at += hc * wt_;
        ac += hc * wc_;
    }
    float vt = (l < NTYPE) ? at : -INFINITY;
    float mt = vt;
    mt = fmaxf(mt, __shfl_xor(mt, 16, 32));
    mt = fmaxf(mt, __shfl_xor(mt, 8, 32));
    mt = fmaxf(mt, __shfl_xor(mt, 4, 32));
    mt = fmaxf(mt, __shfl_xor(mt, 2, 32));
    mt = fmaxf(mt, __shfl_xor(mt, 1, 32));
    float et = __expf(vt - mt);
    float stt = et;
    stt += __shfl_xor(stt, 16, 32);
    stt += __shfl_xor(stt, 8, 32);
    stt += __shfl_xor(stt, 4, 32);
    stt += __shfl_xor(stt, 2, 32);
    stt += __shfl_xor(stt, 1, 32);
    float lt = vt - mt - logf(stt);
    float vc = (l < NCLONE) ? ac : -INFINITY;
    float mc = vc;
    mc = fmaxf(mc, __shfl_xor(mc, 16, 32));
    mc = fmaxf(mc, __shfl_xor(mc, 8, 32));
    mc = fmaxf(mc, __shfl_xor(mc, 4, 32));
    mc = fmaxf(mc, __shfl_xor(mc, 2, 32));
    mc = fmaxf(mc, __shfl_xor(mc, 1, 32));
    float ec = __expf(vc - mc);
    float sc = ec;
    sc += __shfl_xor(sc, 16, 32);
    sc += __shfl_xor(sc, 8, 32);
    sc += __shfl_xor(sc, 4, 32);
    sc += __shfl_xor(sc, 2, 32);
    sc += __shfl_xor(sc, 1, 32);
    float lc = vc - mc - logf(sc);
    size_t ob = (size_t)v * 48;
    if (l < NCLONE) outp[ob + l] = lc;
    if (l < NTYPE) outp[ob + NCLONE + l] = lt;
}

// ---------------------------------------------------------------- launcher
extern "C" void kernel_launch(void* const* d_in, const int* in_sizes, int n_in,
                              void* d_out, int out_size, void* d_ws, size_t ws_size,
                              hipStream_t stream) {
    const float* x     = (const float*)d_in[0];
    const int*   ei    = (const int*)d_in[1];
    const float* ea    = (const float*)d_in[2];
    const float* Wl1   = (const float*)d_in[3];
    const float* Wr1   = (const float*)d_in[4];
    const float* We1   = (const float*)d_in[5];
    const float* att1  = (const float*)d_in[6];
    const float* b1    = (const float*)d_in[7];
    const float* skipW = (const float*)d_in[8];
    const float* skipb = (const float*)d_in[9];
    const float* bng   = (const float*)d_in[10];
    const float* bnb   = (const float*)d_in[11];
    const float* Wl2   = (const float*)d_in[12];
    const float* Wr2   = (const float*)d_in[13];
    const float* We2   = (const float*)d_in[14];
    const float* att2  = (const float*)d_in[15];
    const float* b2    = (const float*)d_in[16];
    const float* fc1W  = (const float*)d_in[17];
    const float* fc1b  = (const float*)d_in[18];
    const float* Wc    = (const float*)d_in[19];
    const float* bc    = (const float*)d_in[20];
    const float* Wt    = (const float*)d_in[21];
    const float* bt    = (const float*)d_in[22];
    float* out = (float*)d_out;
    float* wout = out + (size_t)NN * 48;

    const size_t NF = (size_t)NN * FIN;   // 12.8M
    char* w = (char*)d_ws;
    bf16_t* xb   = (bf16_t*)w;  w += NF * 2;
    bf16_t* xl1b = (bf16_t*)w;  w += NF * 2;
    bf16_t* xr1b = (bf16_t*)w;  w += NF * 2;
    float*  hbuf = (float*)w;   w += NF * 4;
    int4*   ep   = (int4*)w;    w += (size_t)EE * 16;
    int* deg   = (int*)w;   w += (size_t)NN * 4;
    int* offs  = (int*)w;   w += (size_t)NN * 4;
    int* cur   = (int*)w;   w += (size_t)NN * 4;
    float* asum  = (float*)w; w += (size_t)NN * 4;
    float* mattr = (float*)w; w += (size_t)NN * 4;
    float* Mf    = (float*)w; w += (size_t)NN * 4;
    float* Dn    = (float*)w; w += (size_t)NN * 4;
    int*   bsum  = (int*)w;   w += 64 * 4;
    float* bns   = (float*)w; w += 128 * 4;
    float* bnq   = (float*)w; w += 128 * 4;
    float* scl   = (float*)w; w += 128 * 4;
    float* shf   = (float*)w; w += 128 * 4;
    bf16_t* WbT  = (bf16_t*)w; w += 384 * 128 * 2;
    bf16_t* Wb2T = (bf16_t*)w; w += 64 * 128 * 2;
    // aliases into dead regions
    bf16_t* xl2b = xb;                                        // 6.4 MB of xb region
    float*  xr2  = (float*)((char*)d_ws + (size_t)NN * 32 * 2); // after xl2b
    float*  h3   = (float*)xl1b;                              // xl1 region

    hipMemsetAsync(deg, 0, (size_t)NN * 4 * sizeof(int), stream);   // deg, offs, cur, asum
    hipMemsetAsync(bns, 0, 256 * sizeof(float), stream);            // bns, bnq

    k_cvt<<<6250, 256, 0, stream>>>(x, xb);
    k_wcvt<<<224, 256, 0, stream>>>(Wl1, Wr1, skipW, Wl2, Wr2, WbT, Wb2T);

    k_deg<<<6250, 256, 0, stream>>>(ei, ea, deg, asum);
    k_mean<<<391, 256, 0, stream>>>(deg, asum, mattr);
    k_scan1<<<SCAN_B, 256, 0, stream>>>(deg, offs, bsum);
    k_scan2<<<1, 64, 0, stream>>>(bsum);
    k_scan3<<<391, 256, 0, stream>>>(offs, bsum);
    k_fill<<<6250, 256, 0, stream>>>(ei, ea, offs, cur, ep);

    k_gemm1<<<dim3(782, 6), 256, 0, stream>>>(xb, WbT, xl1b, xr1b, hbuf);
    k_gat1<<<25000, 256, 0, stream>>>(xl1b, xr1b, mattr, offs, deg, ep,
                                      att1, We1, b1, skipb, hbuf);
    k_bnstats<<<128, 256, 0, stream>>>(hbuf, bns, bnq);
    k_bnfinal<<<1, 128, 0, stream>>>(bns, bnq, bng, bnb, scl, shf);
    k_gemm2<<<782, 256, 0, stream>>>(hbuf, scl, shf, Wb2T, xl2b, xr2);
    k_gat2<<<12500, 256, 0, stream>>>(xl2b, xr2, mattr, offs, deg, ep,
                                      att2, We2, b2, h3, wout, Mf, Dn);
    k_wfinal<<<6641, 256, 0, stream>>>(ei, Mf, Dn, wout);
    k_head<<<12500, 256, 0, stream>>>(h3, fc1W, fc1b, Wc, bc, Wt, bt, out);
}

// Round 4
// 543.300 us; speedup vs baseline: 1.9847x; 1.2546x over previous
//
#include <hip/hip_runtime.h>
#include <math.h>

// Problem constants
#define NN 100000
#define EE 1600000
#define FIN 128
#define HCH 128     // H*C for gat1
#define CCH 32      // C
#define NCLONE 19
#define NTYPE 29
#define ETOT (EE + NN)
#define SCAN_B 49   // ceil(NN / 2048)

typedef __bf16 bf16_t;
typedef bf16_t bf16x2 __attribute__((ext_vector_type(2)));
typedef bf16_t bf16x4 __attribute__((ext_vector_type(4)));
typedef bf16_t bf16x8 __attribute__((ext_vector_type(8)));
typedef float f32x4 __attribute__((ext_vector_type(4)));

// ---------------------------------------------------------------- weight conversion
// WbT[n][k] (384x128), Wb2T[n][k] (64x128)
__global__ __launch_bounds__(256) void k_wcvt(const float* __restrict__ Wl1,
                                              const float* __restrict__ Wr1,
                                              const float* __restrict__ Ws,
                                              const float* __restrict__ Wl2,
                                              const float* __restrict__ Wr2,
                                              bf16_t* __restrict__ WbT,
                                              bf16_t* __restrict__ Wb2T) {
    int t = blockIdx.x * 256 + threadIdx.x;
    if (t < 384 * 128) {
        int n = t >> 7, k = t & 127;
        const float* W = (n < 128) ? Wl1 : ((n < 256) ? Wr1 : Ws);
        WbT[t] = (bf16_t)W[k * 128 + (n & 127)];
    } else if (t < 384 * 128 + 64 * 128) {
        int u = t - 384 * 128;
        int n = u >> 7, k = u & 127;
        const float* W = (n < 32) ? Wl2 : Wr2;
        Wb2T[u] = (bf16_t)W[k * 32 + (n & 31)];
    }
}

// ---------------------------------------------------------------- degree + slot
__global__ __launch_bounds__(256) void k_deg(const int* __restrict__ ei,
                                             int* __restrict__ deg,
                                             int* __restrict__ slot) {
    int e = blockIdx.x * 256 + threadIdx.x;
    if (e < EE) {
        int d = ei[EE + e];
        slot[e] = atomicAdd(&deg[d], 1);
    }
}

// ---------------------------------------------------------------- exclusive scan of deg
__global__ __launch_bounds__(256) void k_scan1(const int* __restrict__ deg,
                                               int* __restrict__ offs,
                                               int* __restrict__ bsum) {
    __shared__ int tsum[256];
    int b = blockIdx.x, tid = threadIdx.x;
    int base = b * 2048;
    int loc[8];
    int s = 0;
    #pragma unroll
    for (int i = 0; i < 8; ++i) {
        int idx = base + tid * 8 + i;
        int d = (idx < NN) ? deg[idx] : 0;
        loc[i] = s; s += d;
    }
    tsum[tid] = s;
    __syncthreads();
    for (int off = 1; off < 256; off <<= 1) {
        int v = (tid >= off) ? tsum[tid - off] : 0;
        __syncthreads();
        tsum[tid] += v;
        __syncthreads();
    }
    int texcl = tsum[tid] - s;
    #pragma unroll
    for (int i = 0; i < 8; ++i) {
        int idx = base + tid * 8 + i;
        if (idx < NN) offs[idx] = texcl + loc[i];
    }
    if (tid == 255) bsum[b] = tsum[255];
}

__global__ void k_scan2(int* __restrict__ bsum) {
    if (threadIdx.x == 0) {
        int run = 0;
        for (int i = 0; i < SCAN_B; ++i) { int t = bsum[i]; bsum[i] = run; run += t; }
    }
}

__global__ __launch_bounds__(256) void k_scan3(int* __restrict__ offs,
                                               const int* __restrict__ bsum) {
    int i = blockIdx.x * 256 + threadIdx.x;
    if (i < NN) offs[i] += bsum[i >> 11];
}

// ---------------------------------------------------------------- CSR fill (atomic-free)
__global__ __launch_bounds__(256) void k_fill(const int* __restrict__ ei,
                                              const float* __restrict__ ea,
                                              const int* __restrict__ offs,
                                              const int* __restrict__ slot,
                                              int4* __restrict__ ep) {
    int e = blockIdx.x * 256 + threadIdx.x;
    if (e < EE) {
        int d = ei[EE + e];
        int pos = offs[d] + slot[e];
        ep[pos] = make_int4(ei[e], __float_as_int(ea[e]), e, 0);
    }
}

// ---------------------------------------------------------------- mean edge attr per node (CSR, 16 lanes/node)
__global__ __launch_bounds__(256) void k_mean(const int* __restrict__ offs,
                                              const int* __restrict__ deg,
                                              const int4* __restrict__ ep,
                                              float* __restrict__ mattr) {
    int g = (blockIdx.x * 256 + threadIdx.x) >> 4;
    if (g >= NN) return;
    int l = threadIdx.x & 15;
    int st = offs[g], dg = deg[g];
    float s = 0.f;
    for (int i = l; i < dg; i += 16) s += __int_as_float(ep[st + i].y);
    s += __shfl_xor(s, 1, 16);
    s += __shfl_xor(s, 2, 16);
    s += __shfl_xor(s, 4, 16);
    s += __shfl_xor(s, 8, 16);
    if (l == 0) mattr[g] = s / fmaxf((float)dg, 1.0f);
}

// ---------------------------------------------------------------- GEMM1 (MFMA): x(f32) @ WbT^T -> [xl1|xr1|skb] (all bf16)
__global__ __launch_bounds__(256) void k_gemm1(const float* __restrict__ x,
                                               const bf16_t* __restrict__ WbT,
                                               bf16_t* __restrict__ xl,
                                               bf16_t* __restrict__ xr,
                                               bf16_t* __restrict__ sk) {
    __shared__ bf16_t As[128 * 128];
    __shared__ bf16_t Bs[64 * 128];
    const int tid = threadIdx.x;
    const int row0 = blockIdx.x * 128;
    const int col0 = blockIdx.y * 64;
    #pragma unroll
    for (int i = 0; i < 8; ++i) {
        int c = i * 256 + tid;
        int r = c >> 4, g = c & 15;
        int gr = row0 + r;
        bf16x8 v = {};
        if (gr < NN) {
            float4 f0 = *(const float4*)(x + (size_t)gr * 128 + g * 8);
            float4 f1 = *(const float4*)(x + (size_t)gr * 128 + g * 8 + 4);
            v[0] = (bf16_t)f0.x; v[1] = (bf16_t)f0.y; v[2] = (bf16_t)f0.z; v[3] = (bf16_t)f0.w;
            v[4] = (bf16_t)f1.x; v[5] = (bf16_t)f1.y; v[6] = (bf16_t)f1.z; v[7] = (bf16_t)f1.w;
        }
        *(bf16x8*)&As[r * 128 + ((g ^ (r & 7)) * 8)] = v;
    }
    #pragma unroll
    for (int i = 0; i < 4; ++i) {
        int c = i * 256 + tid;
        int n = c >> 4, g = c & 15;
        bf16x8 v = *(const bf16x8*)(WbT + (size_t)(col0 + n) * 128 + g * 8);
        *(bf16x8*)&Bs[n * 128 + ((g ^ (n & 7)) * 8)] = v;
    }
    __syncthreads();

    const int wid = tid >> 6, lane = tid & 63;
    const int wm = wid >> 1, wn = wid & 1;
    const int lr = lane & 15, lg = lane >> 4;
    f32x4 acc[4][2] = {};
    #pragma unroll
    for (int ks = 0; ks < 4; ++ks) {
        int g = ks * 4 + lg;
        bf16x8 b0, b1;
        {
            int n = wn * 32 + lr;
            b0 = *(const bf16x8*)&Bs[n * 128 + ((g ^ (n & 7)) * 8)];
            n += 16;
            b1 = *(const bf16x8*)&Bs[n * 128 + ((g ^ (n & 7)) * 8)];
        }
        #pragma unroll
        for (int mi = 0; mi < 4; ++mi) {
            int r = wm * 64 + mi * 16 + lr;
            bf16x8 a = *(const bf16x8*)&As[r * 128 + ((g ^ (r & 7)) * 8)];
            acc[mi][0] = __builtin_amdgcn_mfma_f32_16x16x32_bf16(a, b0, acc[mi][0], 0, 0, 0);
            acc[mi][1] = __builtin_amdgcn_mfma_f32_16x16x32_bf16(a, b1, acc[mi][1], 0, 0, 0);
        }
    }
    #pragma unroll
    for (int mi = 0; mi < 4; ++mi)
        #pragma unroll
        for (int ni = 0; ni < 2; ++ni)
            #pragma unroll
            for (int j = 0; j < 4; ++j) {
                int gr = row0 + wm * 64 + mi * 16 + lg * 4 + j;
                if (gr >= NN) continue;
                int n = col0 + wn * 32 + ni * 16 + lr;
                float val = acc[mi][ni][j];
                if (n < 128) xl[(size_t)gr * 128 + n] = (bf16_t)val;
                else if (n < 256) xr[(size_t)gr * 128 + (n - 128)] = (bf16_t)val;
                else sk[(size_t)gr * 128 + (n - 256)] = (bf16_t)val;
            }
}

// ---------------------------------------------------------------- GAT1: one wave per node, 2 edges in flight (half-waves)
// 32 lanes x 4ch per edge; head = 8 lanes; independent online-softmax state per half, merged at end.
__global__ __launch_bounds__(256) void k_gat1(const bf16_t* __restrict__ xl1,
                                              const bf16_t* __restrict__ xr1,
                                              const bf16_t* __restrict__ skb,
                                              const float* __restrict__ mattr,
                                              const int* __restrict__ offs,
                                              const int* __restrict__ deg,
                                              const int4* __restrict__ ep,
                                              const float* __restrict__ att1,
                                              const float* __restrict__ we1,
                                              const float* __restrict__ b1,
                                              const float* __restrict__ skipb,
                                              bf16_t* __restrict__ hb) {
    int v = (blockIdx.x * 256 + threadIdx.x) >> 6;
    if (v >= NN) return;
    int lane = threadIdx.x & 63;
    int half = lane >> 5;
    int l = lane & 31;
    int c0 = l * 4;
    float4 at = *(const float4*)(att1 + c0);
    float4 we = *(const float4*)(we1 + c0);
    bf16x4 xrv = *(const bf16x4*)(xr1 + (size_t)v * 128 + c0);
    float xr0 = (float)xrv[0], xr1_ = (float)xrv[1], xr2_ = (float)xrv[2], xr3_ = (float)xrv[3];
    float eav = mattr[v];
    // self loop (computed by both halves; only half 0 keeps it)
    bf16x4 svv = *(const bf16x4*)(xl1 + (size_t)v * 128 + c0);
    float s0 = (float)svv[0], s1 = (float)svv[1], s2 = (float)svv[2], s3 = (float)svv[3];
    {
    }
    float u0 = s0 + fmaf(eav, we.x, xr0); u0 = (u0 > 0.f) ? u0 : 0.2f * u0;
    float u1 = s1 + fmaf(eav, we.y, xr1_); u1 = (u1 > 0.f) ? u1 : 0.2f * u1;
    float u2 = s2 + fmaf(eav, we.z, xr2_); u2 = (u2 > 0.f) ? u2 : 0.2f * u2;
    float u3 = s3 + fmaf(eav, we.w, xr3_); u3 = (u3 > 0.f) ? u3 : 0.2f * u3;
    float p = fmaf(u0, at.x, fmaf(u1, at.y, fmaf(u2, at.z, u3 * at.w)));
    p += __shfl_xor(p, 1, 8);
    p += __shfl_xor(p, 2, 8);
    p += __shfl_xor(p, 4, 8);
    float mr, den, n0, n1, n2, n3;
    if (half == 0) { mr = p; den = 1.f; n0 = s0; n1 = s1; n2 = s2; n3 = s3; }
    else { mr = -1e30f; den = 0.f; n0 = n1 = n2 = n3 = 0.f; }
    int st = offs[v], dg = deg[v];
    for (int i = half; i < dg; i += 2) {
        int4 e = ep[st + i];
        bf16x4 a = *(const bf16x4*)(xl1 + (size_t)e.x * 128 + c0);
        float ea_ = __int_as_float(e.y);
        float x0 = (float)a[0], x1 = (float)a[1], x2 = (float)a[2], x3 = (float)a[3];
        float w0 = x0 + fmaf(ea_, we.x, xr0); w0 = (w0 > 0.f) ? w0 : 0.2f * w0;
        float w1 = x1 + fmaf(ea_, we.y, xr1_); w1 = (w1 > 0.f) ? w1 : 0.2f * w1;
        float w2 = x2 + fmaf(ea_, we.z, xr2_); w2 = (w2 > 0.f) ? w2 : 0.2f * w2;
        float w3 = x3 + fmaf(ea_, we.w, xr3_); w3 = (w3 > 0.f) ? w3 : 0.2f * w3;
        float q = fmaf(w0, at.x, fmaf(w1, at.y, fmaf(w2, at.z, w3 * at.w)));
        q += __shfl_xor(q, 1, 8);
        q += __shfl_xor(q, 2, 8);
        q += __shfl_xor(q, 4, 8);
        float nm = fmaxf(mr, q);
        float ex = __expf(q - nm);
        if (nm > mr) {
            float sc = __expf(mr - nm);
            den *= sc; n0 *= sc; n1 *= sc; n2 *= sc; n3 *= sc; mr = nm;
        }
        den += ex;
        n0 = fmaf(ex, x0, n0); n1 = fmaf(ex, x1, n1);
        n2 = fmaf(ex, x2, n2); n3 = fmaf(ex, x3, n3);
    }
    // merge the two half-wave states
    {
        float mo = __shfl_xor(mr, 32, 64);
        float dn = __shfl_xor(den, 32, 64);
        float o0 = __shfl_xor(n0, 32, 64);
        float o1 = __shfl_xor(n1, 32, 64);
        float o2 = __shfl_xor(n2, 32, 64);
        float o3 = __shfl_xor(n3, 32, 64);
        float M = fmaxf(mr, mo);
        float sa = __expf(mr - M), sb = __expf(mo - M);
        den = den * sa + dn * sb;
        n0 = n0 * sa + o0 * sb; n1 = n1 * sa + o1 * sb;
        n2 = n2 * sa + o2 * sb; n3 = n3 * sa + o3 * sb;
    }
    if (half == 0) {
        float inv = 1.0f / (den + 1e-16f);
        float4 bb = *(const float4*)(b1 + c0);
        float4 sbv = *(const float4*)(skipb + c0);
        bf16x4 skv = *(const bf16x4*)(skb + (size_t)v * 128 + c0);
        bf16x4 r;
        r[0] = (bf16_t)(n0 * inv + bb.x + (float)skv[0] + sbv.x);
        r[1] = (bf16_t)(n1 * inv + bb.y + (float)skv[1] + sbv.y);
        r[2] = (bf16_t)(n2 * inv + bb.z + (float)skv[2] + sbv.z);
        r[3] = (bf16_t)(n3 * inv + bb.w + (float)skv[3] + sbv.w);
        *(bf16x4*)(hb + (size_t)v * 128 + c0) = r;
    }
}

// ---------------------------------------------------------------- batchnorm stats (bf16 input, per-block LDS reduce)
__global__ __launch_bounds__(256) void k_bnstats(const bf16_t* __restrict__ h,
                                                 float* __restrict__ bns,
                                                 float* __restrict__ bnq) {
    __shared__ float sS[16 * 128];
    __shared__ float sQ[16 * 128];
    int tid = threadIdx.x;
    int cg = tid & 15;          // 8 channels per lane
    int slot = tid >> 4;        // 16 row slots
    int c0 = cg * 8;
    float s[8] = {}, q[8] = {};
    for (int r = blockIdx.x * 16 + slot; r < NN; r += gridDim.x * 16) {
        bf16x8 v = *(const bf16x8*)&h[(size_t)r * 128 + c0];
        #pragma unroll
        for (int j = 0; j < 8; ++j) { float f = (float)v[j]; s[j] += f; q[j] += f * f; }
    }
    #pragma unroll
    for (int j = 0; j < 8; ++j) { sS[slot * 128 + c0 + j] = s[j]; sQ[slot * 128 + c0 + j] = q[j]; }
    __syncthreads();
    if (tid < 128) {
        float as = 0.f, aq = 0.f;
        #pragma unroll
        for (int k = 0; k < 16; ++k) { as += sS[k * 128 + tid]; aq += sQ[k * 128 + tid]; }
        atomicAdd(&bns[tid], as);
        atomicAdd(&bnq[tid], aq);
    }
}

__global__ void k_bnfinal(const float* __restrict__ bns, const float* __restrict__ bnq,
                          const float* __restrict__ g, const float* __restrict__ b,
                          float* __restrict__ scale, float* __restrict__ shift) {
    int c = threadIdx.x;
    if (c < 128) {
        float mu = bns[c] * (1.0f / NN);
        float var = bnq[c] * (1.0f / NN) - mu * mu;
        float rs = rsqrtf(var + 1e-5f);
        float a = rs * g[c];
        scale[c] = a;
        shift[c] = b[c] - mu * a;
    }
}

// ---------------------------------------------------------------- GEMM2 (MFMA): elu(bn(h_bf16)) @ Wb2T^T -> [xl2 bf16 | xr2 f32]
__global__ __launch_bounds__(256) void k_gemm2(const bf16_t* __restrict__ h,
                                               const float* __restrict__ scl,
                                               const float* __restrict__ shf,
                                               const bf16_t* __restrict__ Wb2T,
                                               bf16_t* __restrict__ xl2,
                                               float* __restrict__ xr2) {
    __shared__ bf16_t As[128 * 128];
    __shared__ bf16_t Bs[64 * 128];
    const int tid = threadIdx.x;
    const int row0 = blockIdx.x * 128;
    #pragma unroll
    for (int i = 0; i < 8; ++i) {
        int c = i * 256 + tid;
        int r = c >> 4, g = c & 15;
        int gr = row0 + r;
        bf16x8 v = {};
        if (gr < NN) {
            bf16x8 hv = *(const bf16x8*)(h + (size_t)gr * 128 + g * 8);
            float4 s0 = *(const float4*)(scl + g * 8);
            float4 s1 = *(const float4*)(scl + g * 8 + 4);
            float4 t0 = *(const float4*)(shf + g * 8);
            float4 t1 = *(const float4*)(shf + g * 8 + 4);
            float e[8];
            e[0] = (float)hv[0] * s0.x + t0.x; e[1] = (float)hv[1] * s0.y + t0.y;
            e[2] = (float)hv[2] * s0.z + t0.z; e[3] = (float)hv[3] * s0.w + t0.w;
            e[4] = (float)hv[4] * s1.x + t1.x; e[5] = (float)hv[5] * s1.y + t1.y;
            e[6] = (float)hv[6] * s1.z + t1.z; e[7] = (float)hv[7] * s1.w + t1.w;
            #pragma unroll
            for (int j = 0; j < 8; ++j) {
                float vv = e[j];
                vv = (vv > 0.f) ? vv : (__expf(vv) - 1.0f);
                v[j] = (bf16_t)vv;
            }
        }
        *(bf16x8*)&As[r * 128 + ((g ^ (r & 7)) * 8)] = v;
    }
    #pragma unroll
    for (int i = 0; i < 4; ++i) {
        int c = i * 256 + tid;
        int n = c >> 4, g = c & 15;
        bf16x8 v = *(const bf16x8*)(Wb2T + (size_t)n * 128 + g * 8);
        *(bf16x8*)&Bs[n * 128 + ((g ^ (n & 7)) * 8)] = v;
    }
    __syncthreads();

    const int wid = tid >> 6, lane = tid & 63;
    const int wm = wid >> 1, wn = wid & 1;
    const int lr = lane & 15, lg = lane >> 4;
    f32x4 acc[4][2] = {};
    #pragma unroll
    for (int ks = 0; ks < 4; ++ks) {
        int g = ks * 4 + lg;
        bf16x8 b0, b1;
        {
            int n = wn * 32 + lr;
            b0 = *(const bf16x8*)&Bs[n * 128 + ((g ^ (n & 7)) * 8)];
            n += 16;
            b1 = *(const bf16x8*)&Bs[n * 128 + ((g ^ (n & 7)) * 8)];
        }
        #pragma unroll
        for (int mi = 0; mi < 4; ++mi) {
            int r = wm * 64 + mi * 16 + lr;
            bf16x8 a = *(const bf16x8*)&As[r * 128 + ((g ^ (r & 7)) * 8)];
            acc[mi][0] = __builtin_amdgcn_mfma_f32_16x16x32_bf16(a, b0, acc[mi][0], 0, 0, 0);
            acc[mi][1] = __builtin_amdgcn_mfma_f32_16x16x32_bf16(a, b1, acc[mi][1], 0, 0, 0);
        }
    }
    #pragma unroll
    for (int mi = 0; mi < 4; ++mi)
        #pragma unroll
        for (int ni = 0; ni < 2; ++ni)
            #pragma unroll
            for (int j = 0; j < 4; ++j) {
                int gr = row0 + wm * 64 + mi * 16 + lg * 4 + j;
                if (gr >= NN) continue;
                int n = wn * 32 + ni * 16 + lr;
                float val = acc[mi][ni][j];
                if (n < 32) xl2[(size_t)gr * 32 + n] = (bf16_t)val;
                else xr2[(size_t)gr * 32 + (n - 32)] = val;
            }
}

// ---------------------------------------------------------------- GAT2: one wave per node, 4 edges in flight (quads)
__global__ __launch_bounds__(256) void k_gat2(const bf16_t* __restrict__ xl2,
                                              const float* __restrict__ xr2,
                                              const float* __restrict__ mattr,
                                              const int* __restrict__ offs,
                                              const int* __restrict__ deg,
                                              const int4* __restrict__ ep,
                                              const float* __restrict__ att2,
                                              const float* __restrict__ we2,
                                              const float* __restrict__ b2,
                                              float* __restrict__ h3,
                                              float* __restrict__ wout,
                                              float* __restrict__ Mf,
                                              float* __restrict__ Dn) {
    int v = (blockIdx.x * 256 + threadIdx.x) >> 6;
    if (v >= NN) return;
    int lane = threadIdx.x & 63;
    int quad = lane >> 4;
    int l = lane & 15;
    int c0 = l * 2;
    float2 xr = *(const float2*)(xr2 + (size_t)v * 32 + c0);
    float2 at = *(const float2*)(att2 + c0);
    float2 we = *(const float2*)(we2 + c0);
    float eav = mattr[v];
    // self loop
    bf16x2 sv = *(const bf16x2*)(xl2 + (size_t)v * 32 + c0);
    float xs0 = (float)sv[0], xs1 = (float)sv[1];
    float u0 = xs0 + fmaf(eav, we.x, xr.x); u0 = (u0 > 0.f) ? u0 : 0.2f * u0;
    float u1 = xs1 + fmaf(eav, we.y, xr.y); u1 = (u1 > 0.f) ? u1 : 0.2f * u1;
    float p = fmaf(u0, at.x, u1 * at.y);
    p += __shfl_xor(p, 1, 16);
    p += __shfl_xor(p, 2, 16);
    p += __shfl_xor(p, 4, 16);
    p += __shfl_xor(p, 8, 16);
    if (lane == 0) wout[EE + v] = p;
    float mr, den, n0, n1;
    if (quad == 0) { mr = p; den = 1.f; n0 = xs0; n1 = xs1; }
    else { mr = -1e30f; den = 0.f; n0 = 0.f; n1 = 0.f; }
    int st = offs[v], dg = deg[v];
    for (int i = quad; i < dg; i += 4) {
        int4 e = ep[st + i];
        bf16x2 a = *(const bf16x2*)(xl2 + (size_t)e.x * 32 + c0);
        float ea_ = __int_as_float(e.y);
        float x0 = (float)a[0], x1 = (float)a[1];
        float w0 = x0 + fmaf(ea_, we.x, xr.x); w0 = (w0 > 0.f) ? w0 : 0.2f * w0;
        float w1 = x1 + fmaf(ea_, we.y, xr.y); w1 = (w1 > 0.f) ? w1 : 0.2f * w1;
        float q = fmaf(w0, at.x, w1 * at.y);
        q += __shfl_xor(q, 1, 16);
        q += __shfl_xor(q, 2, 16);
        q += __shfl_xor(q, 4, 16);
        q += __shfl_xor(q, 8, 16);
        if (l == 0) wout[e.z] = q;
        float nm = fmaxf(mr, q);
        float ex = __expf(q - nm);
        if (nm > mr) {
            float sc = __expf(mr - nm);
            den *= sc; n0 *= sc; n1 *= sc; mr = nm;
        }
        den += ex;
        n0 = fmaf(ex, x0, n0);
        n1 = fmaf(ex, x1, n1);
    }
    // merge 4 quad states: xor16 then xor32
    #pragma unroll
    for (int w_ = 16; w_ <= 32; w_ <<= 1) {
        float mo = __shfl_xor(mr, w_, 64);
        float dn = __shfl_xor(den, w_, 64);
        float o0 = __shfl_xor(n0, w_, 64);
        float o1 = __shfl_xor(n1, w_, 64);
        float M = fmaxf(mr, mo);
        float sa = __expf(mr - M), sb = __expf(mo - M);
        mr = M;
        den = den * sa + dn * sb;
        n0 = n0 * sa + o0 * sb;
        n1 = n1 * sa + o1 * sb;
    }
    if (lane == 0) { Mf[v] = mr; Dn[v] = den; }
    if (quad == 0) {
        float inv = 1.0f / (den + 1e-16f);
        float2 bb = *(const float2*)(b2 + c0);
        float o0 = n0 * inv + bb.x;
        float o1 = n1 * inv + bb.y;
        float2 r;
        r.x = (o0 > 0.f) ? o0 : (__expf(o0) - 1.0f);
        r.y = (o1 > 0.f) ? o1 : (__expf(o1) - 1.0f);
        *(float2*)(h3 + (size_t)v * 32 + c0) = r;
    }
}

// ---------------------------------------------------------------- finalize attention weights w
__global__ __launch_bounds__(256) void k_wfinal(const int* __restrict__ ei,
                                                const float* __restrict__ Mf,
                                                const float* __restrict__ Dn,
                                                float* __restrict__ wout) {
    int e = blockIdx.x * 256 + threadIdx.x;
    if (e >= ETOT) return;
    int d = (e < EE) ? ei[EE + e] : (e - EE);
    float al = wout[e];
    wout[e] = __expf(al - Mf[d]) / (Dn[d] + 1e-16f);
}

// ---------------------------------------------------------------- heads
__global__ __launch_bounds__(256) void k_head(const float* __restrict__ h3,
                                              const float* __restrict__ fc1W,
                                              const float* __restrict__ fc1b,
                                              const float* __restrict__ Wc,
                                              const float* __restrict__ bc,
                                              const float* __restrict__ Wt,
                                              const float* __restrict__ bt,
                                              float* __restrict__ outp) {
    __shared__ float sW1[32 * 32];
    __shared__ float sWc[32 * NCLONE];
    __shared__ float sWt[32 * NTYPE];
    __shared__ float sb1[32], sbc[NCLONE], sbt[NTYPE];
    int tid = threadIdx.x;
    for (int i = tid; i < 1024; i += 256) sW1[i] = fc1W[i];
    for (int i = tid; i < 32 * NCLONE; i += 256) sWc[i] = Wc[i];
    for (int i = tid; i < 32 * NTYPE; i += 256) sWt[i] = Wt[i];
    if (tid < 32) sb1[tid] = fc1b[tid];
    if (tid < NCLONE) sbc[tid] = bc[tid];
    if (tid < NTYPE) sbt[tid] = bt[tid];
    __syncthreads();
    int g = tid >> 5, l = tid & 31;
    int v = blockIdx.x * 8 + g;
    if (v >= NN) return;
    float x = h3[(size_t)v * CCH + l];
    float acc = sb1[l];
    #pragma unroll
    for (int c = 0; c < 32; ++c) {
        float xc = __shfl(x, c, 32);
        acc += xc * sW1[c * 32 + l];
    }
    float hl = fmaxf(acc, 0.0f);
    float at = (l < NTYPE) ? sbt[l] : 0.0f;
    float ac = (l < NCLONE) ? sbc[l] : 0.0f;
    #pragma unroll
    for (int c = 0; c < 32; ++c) {
        float hc = __shfl(hl, c, 32);
        float wt_ = (l < NTYPE) ? sWt[c * NTYPE + l] : 0.0f;
        float wc_ = (l < NCLONE) ? sWc[c * NCLONE + l] : 0.0f;
        at += hc * wt_;
        ac += hc * wc_;
    }
    float vt = (l < NTYPE) ? at : -INFINITY;
    float mt = vt;
    mt = fmaxf(mt, __shfl_xor(mt, 16, 32));
    mt = fmaxf(mt, __shfl_xor(mt, 8, 32));
    mt = fmaxf(mt, __shfl_xor(mt, 4, 32));
    mt = fmaxf(mt, __shfl_xor(mt, 2, 32));
    mt = fmaxf(mt, __shfl_xor(mt, 1, 32));
    float et = __expf(vt - mt);
    float stt = et;
    stt += __shfl_xor(stt, 16, 32);
    stt += __shfl_xor(stt, 8, 32);
    stt += __shfl_xor(stt, 4, 32);
    stt += __shfl_xor(stt, 2, 32);
    stt += __shfl_xor(stt, 1, 32);
    float lt = vt - mt - logf(stt);
    float vc = (l < NCLONE) ? ac : -INFINITY;
    float mc = vc;
    mc = fmaxf(mc, __shfl_xor(mc, 16, 32));
    mc = fmaxf(mc, __shfl_xor(mc, 8, 32));
    mc = fmaxf(mc, __shfl_xor(mc, 4, 32));
    mc = fmaxf(mc, __shfl_xor(mc, 2, 32));
    mc = fmaxf(mc, __shfl_xor(mc, 1, 32));
    float ec = __expf(vc - mc);
    float sc = ec;
    sc += __shfl_xor(sc, 16, 32);
    sc += __shfl_xor(sc, 8, 32);
    sc += __shfl_xor(sc, 4, 32);
    sc += __shfl_xor(sc, 2, 32);
    sc += __shfl_xor(sc, 1, 32);
    float lc = vc - mc - logf(sc);
    size_t ob = (size_t)v * 48;
    if (l < NCLONE) outp[ob + l] = lc;
    if (l < NTYPE) outp[ob + NCLONE + l] = lt;
}

// ---------------------------------------------------------------- launcher
extern "C" void kernel_launch(void* const* d_in, const int* in_sizes, int n_in,
                              void* d_out, int out_size, void* d_ws, size_t ws_size,
                              hipStream_t stream) {
    const float* x     = (const float*)d_in[0];
    const int*   ei    = (const int*)d_in[1];
    const float* ea    = (const float*)d_in[2];
    const float* Wl1   = (const float*)d_in[3];
    const float* Wr1   = (const float*)d_in[4];
    const float* We1   = (const float*)d_in[5];
    const float* att1  = (const float*)d_in[6];
    const float* b1    = (const float*)d_in[7];
    const float* skipW = (const float*)d_in[8];
    const float* skipb = (const float*)d_in[9];
    const float* bng   = (const float*)d_in[10];
    const float* bnb   = (const float*)d_in[11];
    const float* Wl2   = (const float*)d_in[12];
    const float* Wr2   = (const float*)d_in[13];
    const float* We2   = (const float*)d_in[14];
    const float* att2  = (const float*)d_in[15];
    const float* b2    = (const float*)d_in[16];
    const float* fc1W  = (const float*)d_in[17];
    const float* fc1b  = (const float*)d_in[18];
    const float* Wc    = (const float*)d_in[19];
    const float* bc    = (const float*)d_in[20];
    const float* Wt    = (const float*)d_in[21];
    const float* bt    = (const float*)d_in[22];
    float* out = (float*)d_out;
    float* wout = out + (size_t)NN * 48;

    const size_t NF = (size_t)NN * FIN;   // 12.8M elems
    char* w = (char*)d_ws;
    bf16_t* xl1b = (bf16_t*)w;  w += NF * 2;
    bf16_t* xr1b = (bf16_t*)w;  w += NF * 2;
    bf16_t* skb  = (bf16_t*)w;  w += NF * 2;
    bf16_t* hb   = (bf16_t*)w;  w += NF * 2;
    int4*   ep   = (int4*)w;    w += (size_t)EE * 16;
    int*    slot = (int*)w;     w += (size_t)EE * 4;
    int* deg   = (int*)w;   w += (size_t)NN * 4;
    int* offs  = (int*)w;   w += (size_t)NN * 4;
    float* mattr = (float*)w; w += (size_t)NN * 4;
    float* Mf    = (float*)w; w += (size_t)NN * 4;
    float* Dn    = (float*)w; w += (size_t)NN * 4;
    int*   bsum  = (int*)w;   w += 64 * 4;
    float* bns   = (float*)w; w += 128 * 4;
    float* bnq   = (float*)w; w += 128 * 4;
    float* scl   = (float*)w; w += 128 * 4;
    float* shf   = (float*)w; w += 128 * 4;
    bf16_t* WbT  = (bf16_t*)w; w += 384 * 128 * 2;
    bf16_t* Wb2T = (bf16_t*)w; w += 64 * 128 * 2;
    // aliases into dead regions (after gat1):
    bf16_t* xl2b = xl1b;              // 6.4 MB
    float*  xr2  = (float*)xr1b;      // 12.8 MB
    float*  h3   = (float*)skb;       // 12.8 MB

    hipMemsetAsync(deg, 0, (size_t)NN * sizeof(int), stream);
    hipMemsetAsync(bns, 0, 256 * sizeof(float), stream);   // bns + bnq

    k_wcvt<<<224, 256, 0, stream>>>(Wl1, Wr1, skipW, Wl2, Wr2, WbT, Wb2T);

    k_deg<<<6250, 256, 0, stream>>>(ei, deg, slot);
    k_scan1<<<SCAN_B, 256, 0, stream>>>(deg, offs, bsum);
    k_scan2<<<1, 64, 0, stream>>>(bsum);
    k_scan3<<<391, 256, 0, stream>>>(offs, bsum);
    k_fill<<<6250, 256, 0, stream>>>(ei, ea, offs, slot, ep);
    k_mean<<<6250, 256, 0, stream>>>(offs, deg, ep, mattr);

    k_gemm1<<<dim3(782, 6), 256, 0, stream>>>(x, WbT, xl1b, xr1b, skb);
    k_gat1<<<25000, 256, 0, stream>>>(xl1b, xr1b, skb, mattr, offs, deg, ep,
                                      att1, We1, b1, skipb, hb);
    k_bnstats<<<128, 256, 0, stream>>>(hb, bns, bnq);
    k_bnfinal<<<1, 128, 0, stream>>>(bns, bnq, bng, bnb, scl, shf);
    k_gemm2<<<782, 256, 0, stream>>>(hb, scl, shf, Wb2T, xl2b, xr2);
    k_gat2<<<25000, 256, 0, stream>>>(xl2b, xr2, mattr, offs, deg, ep,
                                      att2, We2, b2, h3, wout, Mf, Dn);
    k_wfinal<<<6641, 256, 0, stream>>>(ei, Mf, Dn, wout);
    k_head<<<12500, 256, 0, stream>>>(h3, fc1W, fc1b, Wc, bc, Wt, bt, out);
}

// Round 5
// 484.971 us; speedup vs baseline: 2.2234x; 1.1203x over previous
//
#include <hip/hip_runtime.h>
#include <math.h>

// Problem constants
#define NN 100000
#define EE 1600000
#define FIN 128
#define HCH 128     // H*C for gat1
#define CCH 32      // C
#define NCLONE 19
#define NTYPE 29
#define ETOT (EE + NN)
#define SCAN_B 49   // ceil(NN / 2048)

typedef __bf16 bf16_t;
typedef bf16_t bf16x2 __attribute__((ext_vector_type(2)));
typedef bf16_t bf16x4 __attribute__((ext_vector_type(4)));
typedef bf16_t bf16x8 __attribute__((ext_vector_type(8)));
typedef float f32x4 __attribute__((ext_vector_type(4)));

// ---------------------------------------------------------------- weight conversion
// WbT[n][k] (384x128), Wb2T[n][k] (64x128)
__global__ __launch_bounds__(256) void k_wcvt(const float* __restrict__ Wl1,
                                              const float* __restrict__ Wr1,
                                              const float* __restrict__ Ws,
                                              const float* __restrict__ Wl2,
                                              const float* __restrict__ Wr2,
                                              bf16_t* __restrict__ WbT,
                                              bf16_t* __restrict__ Wb2T) {
    int t = blockIdx.x * 256 + threadIdx.x;
    if (t < 384 * 128) {
        int n = t >> 7, k = t & 127;
        const float* W = (n < 128) ? Wl1 : ((n < 256) ? Wr1 : Ws);
        WbT[t] = (bf16_t)W[k * 128 + (n & 127)];
    } else if (t < 384 * 128 + 64 * 128) {
        int u = t - 384 * 128;
        int n = u >> 7, k = u & 127;
        const float* W = (n < 32) ? Wl2 : Wr2;
        Wb2T[u] = (bf16_t)W[k * 32 + (n & 31)];
    }
}

// ---------------------------------------------------------------- degree + slot
__global__ __launch_bounds__(256) void k_deg(const int* __restrict__ ei,
                                             int* __restrict__ deg,
                                             int* __restrict__ slot) {
    int e = blockIdx.x * 256 + threadIdx.x;
    if (e < EE) {
        int d = ei[EE + e];
        slot[e] = atomicAdd(&deg[d], 1);
    }
}

// ---------------------------------------------------------------- exclusive scan of deg
__global__ __launch_bounds__(256) void k_scan1(const int* __restrict__ deg,
                                               int* __restrict__ offs,
                                               int* __restrict__ bsum) {
    __shared__ int tsum[256];
    int b = blockIdx.x, tid = threadIdx.x;
    int base = b * 2048;
    int loc[8];
    int s = 0;
    #pragma unroll
    for (int i = 0; i < 8; ++i) {
        int idx = base + tid * 8 + i;
        int d = (idx < NN) ? deg[idx] : 0;
        loc[i] = s; s += d;
    }
    tsum[tid] = s;
    __syncthreads();
    for (int off = 1; off < 256; off <<= 1) {
        int v = (tid >= off) ? tsum[tid - off] : 0;
        __syncthreads();
        tsum[tid] += v;
        __syncthreads();
    }
    int texcl = tsum[tid] - s;
    #pragma unroll
    for (int i = 0; i < 8; ++i) {
        int idx = base + tid * 8 + i;
        if (idx < NN) offs[idx] = texcl + loc[i];
    }
    if (tid == 255) bsum[b] = tsum[255];
}

__global__ void k_scan2(int* __restrict__ bsum) {
    if (threadIdx.x == 0) {
        int run = 0;
        for (int i = 0; i < SCAN_B; ++i) { int t = bsum[i]; bsum[i] = run; run += t; }
    }
}

__global__ __launch_bounds__(256) void k_scan3(int* __restrict__ offs,
                                               const int* __restrict__ bsum) {
    int i = blockIdx.x * 256 + threadIdx.x;
    if (i < NN) offs[i] += bsum[i >> 11];
}

// ---------------------------------------------------------------- CSR fill (atomic-free)
__global__ __launch_bounds__(256) void k_fill(const int* __restrict__ ei,
                                              const float* __restrict__ ea,
                                              const int* __restrict__ offs,
                                              const int* __restrict__ slot,
                                              int2* __restrict__ ep8,
                                              int* __restrict__ eid) {
    int e = blockIdx.x * 256 + threadIdx.x;
    if (e < EE) {
        int d = ei[EE + e];
        int pos = offs[d] + slot[e];
        ep8[pos] = make_int2(ei[e], __float_as_int(ea[e]));
        eid[pos] = e;
    }
}

// ---------------------------------------------------------------- GEMM1 (MFMA): x(f32) @ WbT^T -> chunk (bf16)
// BM=128, BN=128, K=128. 4 waves (2x2), wave tile 64x64.
__global__ __launch_bounds__(256) void k_gemm1(const float* __restrict__ x,
                                               const bf16_t* __restrict__ WbT,
                                               bf16_t* __restrict__ xl,
                                               bf16_t* __restrict__ xr,
                                               bf16_t* __restrict__ sk) {
    __shared__ bf16_t As[128 * 128];
    __shared__ bf16_t Bs[128 * 128];
    const int tid = threadIdx.x;
    const int row0 = blockIdx.x * 128;
    const int chunk = blockIdx.y;
    const int col0 = chunk * 128;
    bf16_t* __restrict__ out = (chunk == 0) ? xl : ((chunk == 1) ? xr : sk);
    #pragma unroll
    for (int i = 0; i < 8; ++i) {
        int c = i * 256 + tid;
        int r = c >> 4, g = c & 15;
        int gr = row0 + r;
        bf16x8 v = {};
        if (gr < NN) {
            float4 f0 = *(const float4*)(x + (size_t)gr * 128 + g * 8);
            float4 f1 = *(const float4*)(x + (size_t)gr * 128 + g * 8 + 4);
            v[0] = (bf16_t)f0.x; v[1] = (bf16_t)f0.y; v[2] = (bf16_t)f0.z; v[3] = (bf16_t)f0.w;
            v[4] = (bf16_t)f1.x; v[5] = (bf16_t)f1.y; v[6] = (bf16_t)f1.z; v[7] = (bf16_t)f1.w;
        }
        *(bf16x8*)&As[r * 128 + ((g ^ (r & 7)) * 8)] = v;
    }
    #pragma unroll
    for (int i = 0; i < 8; ++i) {
        int c = i * 256 + tid;
        int n = c >> 4, g = c & 15;
        bf16x8 v = *(const bf16x8*)(WbT + (size_t)(col0 + n) * 128 + g * 8);
        *(bf16x8*)&Bs[n * 128 + ((g ^ (n & 7)) * 8)] = v;
    }
    __syncthreads();

    const int wid = tid >> 6, lane = tid & 63;
    const int wm = wid >> 1, wn = wid & 1;
    const int lr = lane & 15, lg = lane >> 4;
    f32x4 acc[4][4] = {};
    #pragma unroll
    for (int ks = 0; ks < 4; ++ks) {
        int g = ks * 4 + lg;
        bf16x8 b[4];
        #pragma unroll
        for (int ni = 0; ni < 4; ++ni) {
            int n = wn * 64 + ni * 16 + lr;
            b[ni] = *(const bf16x8*)&Bs[n * 128 + ((g ^ (n & 7)) * 8)];
        }
        #pragma unroll
        for (int mi = 0; mi < 4; ++mi) {
            int r = wm * 64 + mi * 16 + lr;
            bf16x8 a = *(const bf16x8*)&As[r * 128 + ((g ^ (r & 7)) * 8)];
            #pragma unroll
            for (int ni = 0; ni < 4; ++ni)
                acc[mi][ni] = __builtin_amdgcn_mfma_f32_16x16x32_bf16(a, b[ni], acc[mi][ni], 0, 0, 0);
        }
    }
    #pragma unroll
    for (int mi = 0; mi < 4; ++mi)
        #pragma unroll
        for (int ni = 0; ni < 4; ++ni)
            #pragma unroll
            for (int j = 0; j < 4; ++j) {
                int gr = row0 + wm * 64 + mi * 16 + lg * 4 + j;
                if (gr >= NN) continue;
                int n = wn * 64 + ni * 16 + lr;
                out[(size_t)gr * 128 + n] = (bf16_t)acc[mi][ni][j];
            }
}

// ---------------------------------------------------------------- GAT1: one wave per node
// 16 lanes x 8ch per edge; 4 edges in flight; depth-2 pipeline; self-loop last (mean attr inline).
__global__ __launch_bounds__(256) void k_gat1(const bf16_t* __restrict__ xl1,
                                              const bf16_t* __restrict__ xr1,
                                              const bf16_t* __restrict__ skb,
                                              const int* __restrict__ offs,
                                              const int* __restrict__ deg,
                                              const int2* __restrict__ ep8,
                                              const float* __restrict__ att1,
                                              const float* __restrict__ we1,
                                              const float* __restrict__ b1,
                                              const float* __restrict__ skipb,
                                              bf16_t* __restrict__ hb,
                                              float* __restrict__ mattr) {
    int v = (blockIdx.x * 256 + threadIdx.x) >> 6;
    if (v >= NN) return;
    int lane = threadIdx.x & 63;
    int sub = lane >> 4;
    int l = lane & 15;
    int c0 = l * 8;
    float at[8], we[8], xr[8];
    {
        float4 t0 = *(const float4*)(att1 + c0);
        float4 t1 = *(const float4*)(att1 + c0 + 4);
        at[0] = t0.x; at[1] = t0.y; at[2] = t0.z; at[3] = t0.w;
        at[4] = t1.x; at[5] = t1.y; at[6] = t1.z; at[7] = t1.w;
        float4 w0 = *(const float4*)(we1 + c0);
        float4 w1 = *(const float4*)(we1 + c0 + 4);
        we[0] = w0.x; we[1] = w0.y; we[2] = w0.z; we[3] = w0.w;
        we[4] = w1.x; we[5] = w1.y; we[6] = w1.z; we[7] = w1.w;
        bf16x8 xrv = *(const bf16x8*)(xr1 + (size_t)v * 128 + c0);
        #pragma unroll
        for (int j = 0; j < 8; ++j) xr[j] = (float)xrv[j];
    }
    float mr = -1e30f, den = 0.f, easum = 0.f;
    float n[8] = {};
    int st = offs[v], dg = deg[v];
    int i = sub;
    int2 e0 = make_int2(0, 0), e1 = make_int2(0, 0);
    bf16x8 a0 = {};
    if (i < dg) e0 = ep8[st + i];
    if (i + 4 < dg) e1 = ep8[st + i + 4];
    if (i < dg) a0 = *(const bf16x8*)(xl1 + (size_t)e0.x * 128 + c0);
    for (; i < dg; i += 4) {
        bf16x8 a1 = {};
        int2 e2 = make_int2(0, 0);
        if (i + 4 < dg) a1 = *(const bf16x8*)(xl1 + (size_t)e1.x * 128 + c0);
        if (i + 8 < dg) e2 = ep8[st + i + 8];
        float ea_ = __int_as_float(e0.y);
        easum += ea_;
        float q = 0.f, xv[8];
        #pragma unroll
        for (int j = 0; j < 8; ++j) {
            xv[j] = (float)a0[j];
            float w_ = xv[j] + fmaf(ea_, we[j], xr[j]);
            w_ = (w_ > 0.f) ? w_ : 0.2f * w_;
            q = fmaf(w_, at[j], q);
        }
        q += __shfl_xor(q, 1, 4);
        q += __shfl_xor(q, 2, 4);
        float nm = fmaxf(mr, q);
        float ex = __expf(q - nm);
        if (nm > mr) {
            float sc = __expf(mr - nm);
            den *= sc;
            #pragma unroll
            for (int j = 0; j < 8; ++j) n[j] *= sc;
            mr = nm;
        }
        den += ex;
        #pragma unroll
        for (int j = 0; j < 8; ++j) n[j] = fmaf(ex, xv[j], n[j]);
        e0 = e1; a0 = a1; e1 = e2;
    }
    // merge 4 subgroup states
    #pragma unroll
    for (int w_ = 16; w_ <= 32; w_ <<= 1) {
        float mo = __shfl_xor(mr, w_, 64);
        float dn = __shfl_xor(den, w_, 64);
        float es = __shfl_xor(easum, w_, 64);
        float o[8];
        #pragma unroll
        for (int j = 0; j < 8; ++j) o[j] = __shfl_xor(n[j], w_, 64);
        float M = fmaxf(mr, mo);
        float sa = __expf(mr - M), sb = __expf(mo - M);
        den = den * sa + dn * sb;
        #pragma unroll
        for (int j = 0; j < 8; ++j) n[j] = n[j] * sa + o[j] * sb;
        mr = M;
        easum += es;
    }
    // self loop (mean edge attr)
    float eav = easum / fmaxf((float)dg, 1.0f);
    if (lane == 0) mattr[v] = eav;
    bf16x8 svv = *(const bf16x8*)(xl1 + (size_t)v * 128 + c0);
    float qs = 0.f, xs[8];
    #pragma unroll
    for (int j = 0; j < 8; ++j) {
        xs[j] = (float)svv[j];
        float w_ = xs[j] + fmaf(eav, we[j], xr[j]);
        w_ = (w_ > 0.f) ? w_ : 0.2f * w_;
        qs = fmaf(w_, at[j], qs);
    }
    qs += __shfl_xor(qs, 1, 4);
    qs += __shfl_xor(qs, 2, 4);
    {
        float nm = fmaxf(mr, qs);
        float ex = __expf(qs - nm);
        if (nm > mr) {
            float sc = __expf(mr - nm);
            den *= sc;
            #pragma unroll
            for (int j = 0; j < 8; ++j) n[j] *= sc;
            mr = nm;
        }
        den += ex;
        #pragma unroll
        for (int j = 0; j < 8; ++j) n[j] = fmaf(ex, xs[j], n[j]);
    }
    if (sub == 0) {
        float inv = 1.0f / (den + 1e-16f);
        float4 bb0 = *(const float4*)(b1 + c0);
        float4 bb1 = *(const float4*)(b1 + c0 + 4);
        float4 sb0 = *(const float4*)(skipb + c0);
        float4 sb1 = *(const float4*)(skipb + c0 + 4);
        bf16x8 skv = *(const bf16x8*)(skb + (size_t)v * 128 + c0);
        float bb[8] = {bb0.x, bb0.y, bb0.z, bb0.w, bb1.x, bb1.y, bb1.z, bb1.w};
        float sv[8] = {sb0.x, sb0.y, sb0.z, sb0.w, sb1.x, sb1.y, sb1.z, sb1.w};
        bf16x8 r;
        #pragma unroll
        for (int j = 0; j < 8; ++j)
            r[j] = (bf16_t)(n[j] * inv + bb[j] + (float)skv[j] + sv[j]);
        *(bf16x8*)(hb + (size_t)v * 128 + c0) = r;
    }
}

// ---------------------------------------------------------------- batchnorm stats (bf16 input, per-block LDS reduce)
__global__ __launch_bounds__(256) void k_bnstats(const bf16_t* __restrict__ h,
                                                 float* __restrict__ bns,
                                                 float* __restrict__ bnq) {
    __shared__ float sS[16 * 128];
    __shared__ float sQ[16 * 128];
    int tid = threadIdx.x;
    int cg = tid & 15;
    int slot = tid >> 4;
    int c0 = cg * 8;
    float s[8] = {}, q[8] = {};
    for (int r = blockIdx.x * 16 + slot; r < NN; r += gridDim.x * 16) {
        bf16x8 v = *(const bf16x8*)&h[(size_t)r * 128 + c0];
        #pragma unroll
        for (int j = 0; j < 8; ++j) { float f = (float)v[j]; s[j] += f; q[j] += f * f; }
    }
    #pragma unroll
    for (int j = 0; j < 8; ++j) { sS[slot * 128 + c0 + j] = s[j]; sQ[slot * 128 + c0 + j] = q[j]; }
    __syncthreads();
    if (tid < 128) {
        float as = 0.f, aq = 0.f;
        #pragma unroll
        for (int k = 0; k < 16; ++k) { as += sS[k * 128 + tid]; aq += sQ[k * 128 + tid]; }
        atomicAdd(&bns[tid], as);
        atomicAdd(&bnq[tid], aq);
    }
}

__global__ void k_bnfinal(const float* __restrict__ bns, const float* __restrict__ bnq,
                          const float* __restrict__ g, const float* __restrict__ b,
                          float* __restrict__ scale, float* __restrict__ shift) {
    int c = threadIdx.x;
    if (c < 128) {
        float mu = bns[c] * (1.0f / NN);
        float var = bnq[c] * (1.0f / NN) - mu * mu;
        float rs = rsqrtf(var + 1e-5f);
        float a = rs * g[c];
        scale[c] = a;
        shift[c] = b[c] - mu * a;
    }
}

// ---------------------------------------------------------------- GEMM2 (MFMA): elu(bn(h_bf16)) @ Wb2T^T -> [xl2 bf16 | xr2 f32]
__global__ __launch_bounds__(256) void k_gemm2(const bf16_t* __restrict__ h,
                                               const float* __restrict__ scl,
                                               const float* __restrict__ shf,
                                               const bf16_t* __restrict__ Wb2T,
                                               bf16_t* __restrict__ xl2,
                                               float* __restrict__ xr2) {
    __shared__ bf16_t As[128 * 128];
    __shared__ bf16_t Bs[64 * 128];
    const int tid = threadIdx.x;
    const int row0 = blockIdx.x * 128;
    #pragma unroll
    for (int i = 0; i < 8; ++i) {
        int c = i * 256 + tid;
        int r = c >> 4, g = c & 15;
        int gr = row0 + r;
        bf16x8 v = {};
        if (gr < NN) {
            bf16x8 hv = *(const bf16x8*)(h + (size_t)gr * 128 + g * 8);
            float4 s0 = *(const float4*)(scl + g * 8);
            float4 s1 = *(const float4*)(scl + g * 8 + 4);
            float4 t0 = *(const float4*)(shf + g * 8);
            float4 t1 = *(const float4*)(shf + g * 8 + 4);
            float e[8];
            e[0] = (float)hv[0] * s0.x + t0.x; e[1] = (float)hv[1] * s0.y + t0.y;
            e[2] = (float)hv[2] * s0.z + t0.z; e[3] = (float)hv[3] * s0.w + t0.w;
            e[4] = (float)hv[4] * s1.x + t1.x; e[5] = (float)hv[5] * s1.y + t1.y;
            e[6] = (float)hv[6] * s1.z + t1.z; e[7] = (float)hv[7] * s1.w + t1.w;
            #pragma unroll
            for (int j = 0; j < 8; ++j) {
                float vv = e[j];
                vv = (vv > 0.f) ? vv : (__expf(vv) - 1.0f);
                v[j] = (bf16_t)vv;
            }
        }
        *(bf16x8*)&As[r * 128 + ((g ^ (r & 7)) * 8)] = v;
    }
    #pragma unroll
    for (int i = 0; i < 4; ++i) {
        int c = i * 256 + tid;
        int n = c >> 4, g = c & 15;
        bf16x8 v = *(const bf16x8*)(Wb2T + (size_t)n * 128 + g * 8);
        *(bf16x8*)&Bs[n * 128 + ((g ^ (n & 7)) * 8)] = v;
    }
    __syncthreads();

    const int wid = tid >> 6, lane = tid & 63;
    const int wm = wid >> 1, wn = wid & 1;
    const int lr = lane & 15, lg = lane >> 4;
    f32x4 acc[4][2] = {};
    #pragma unroll
    for (int ks = 0; ks < 4; ++ks) {
        int g = ks * 4 + lg;
        bf16x8 b0, b1;
        {
            int n = wn * 32 + lr;
            b0 = *(const bf16x8*)&Bs[n * 128 + ((g ^ (n & 7)) * 8)];
            n += 16;
            b1 = *(const bf16x8*)&Bs[n * 128 + ((g ^ (n & 7)) * 8)];
        }
        #pragma unroll
        for (int mi = 0; mi < 4; ++mi) {
            int r = wm * 64 + mi * 16 + lr;
            bf16x8 a = *(const bf16x8*)&As[r * 128 + ((g ^ (r & 7)) * 8)];
            acc[mi][0] = __builtin_amdgcn_mfma_f32_16x16x32_bf16(a, b0, acc[mi][0], 0, 0, 0);
            acc[mi][1] = __builtin_amdgcn_mfma_f32_16x16x32_bf16(a, b1, acc[mi][1], 0, 0, 0);
        }
    }
    #pragma unroll
    for (int mi = 0; mi < 4; ++mi)
        #pragma unroll
        for (int ni = 0; ni < 2; ++ni)
            #pragma unroll
            for (int j = 0; j < 4; ++j) {
                int gr = row0 + wm * 64 + mi * 16 + lg * 4 + j;
                if (gr >= NN) continue;
                int n = wn * 32 + ni * 16 + lr;
                float val = acc[mi][ni][j];
                if (n < 32) xl2[(size_t)gr * 32 + n] = (bf16_t)val;
                else xr2[(size_t)gr * 32 + (n - 32)] = val;
            }
}

// ---------------------------------------------------------------- GAT2: one wave per node, 8 edges in flight, self-normalizing w
__global__ __launch_bounds__(256) void k_gat2(const bf16_t* __restrict__ xl2,
                                              const float* __restrict__ xr2,
                                              const float* __restrict__ mattr,
                                              const int* __restrict__ offs,
                                              const int* __restrict__ deg,
                                              const int2* __restrict__ ep8,
                                              const int* __restrict__ eid,
                                              const float* __restrict__ att2,
                                              const float* __restrict__ we2,
                                              const float* __restrict__ b2,
                                              float* __restrict__ h3,
                                              float* __restrict__ wout) {
    int v = (blockIdx.x * 256 + threadIdx.x) >> 6;
    if (v >= NN) return;
    int lane = threadIdx.x & 63;
    int sub = lane >> 3;
    int l = lane & 7;
    int c0 = l * 4;
    float4 atv = *(const float4*)(att2 + c0);
    float4 wev = *(const float4*)(we2 + c0);
    float4 xrv = *(const float4*)(xr2 + (size_t)v * 32 + c0);
    float at[4] = {atv.x, atv.y, atv.z, atv.w};
    float we[4] = {wev.x, wev.y, wev.z, wev.w};
    float xr[4] = {xrv.x, xrv.y, xrv.z, xrv.w};
    float mr = -1e30f, den = 0.f;
    float n[4] = {};
    int st = offs[v], dg = deg[v];
    int i = sub;
    int2 e0 = make_int2(0, 0), e1 = make_int2(0, 0);
    bf16x4 a0 = {};
    if (i < dg) e0 = ep8[st + i];
    if (i + 8 < dg) e1 = ep8[st + i + 8];
    if (i < dg) a0 = *(const bf16x4*)(xl2 + (size_t)e0.x * 32 + c0);
    for (; i < dg; i += 8) {
        bf16x4 a1 = {};
        int2 e2 = make_int2(0, 0);
        if (i + 8 < dg) a1 = *(const bf16x4*)(xl2 + (size_t)e1.x * 32 + c0);
        if (i + 16 < dg) e2 = ep8[st + i + 16];
        int ide = eid[st + i];
        float ea_ = __int_as_float(e0.y);
        float q = 0.f, xv[4];
        #pragma unroll
        for (int j = 0; j < 4; ++j) {
            xv[j] = (float)a0[j];
            float w_ = xv[j] + fmaf(ea_, we[j], xr[j]);
            w_ = (w_ > 0.f) ? w_ : 0.2f * w_;
            q = fmaf(w_, at[j], q);
        }
        q += __shfl_xor(q, 1, 8);
        q += __shfl_xor(q, 2, 8);
        q += __shfl_xor(q, 4, 8);
        if (l == 0) wout[ide] = q;     // raw alpha; normalized below
        float nm = fmaxf(mr, q);
        float ex = __expf(q - nm);
        if (nm > mr) {
            float sc = __expf(mr - nm);
            den *= sc;
            #pragma unroll
            for (int j = 0; j < 4; ++j) n[j] *= sc;
            mr = nm;
        }
        den += ex;
        #pragma unroll
        for (int j = 0; j < 4; ++j) n[j] = fmaf(ex, xv[j], n[j]);
        e0 = e1; a0 = a1; e1 = e2;
    }
    // merge 8 subgroup states
    #pragma unroll
    for (int w_ = 8; w_ <= 32; w_ <<= 1) {
        float mo = __shfl_xor(mr, w_, 64);
        float dn = __shfl_xor(den, w_, 64);
        float o[4];
        #pragma unroll
        for (int j = 0; j < 4; ++j) o[j] = __shfl_xor(n[j], w_, 64);
        float M = fmaxf(mr, mo);
        float sa = __expf(mr - M), sb = __expf(mo - M);
        den = den * sa + dn * sb;
        #pragma unroll
        for (int j = 0; j < 4; ++j) n[j] = n[j] * sa + o[j] * sb;
        mr = M;
    }
    // self loop
    float eav = mattr[v];
    bf16x4 sv = *(const bf16x4*)(xl2 + (size_t)v * 32 + c0);
    float qs = 0.f, xs[4];
    #pragma unroll
    for (int j = 0; j < 4; ++j) {
        xs[j] = (float)sv[j];
        float w_ = xs[j] + fmaf(eav, we[j], xr[j]);
        w_ = (w_ > 0.f) ? w_ : 0.2f * w_;
        qs = fmaf(w_, at[j], qs);
    }
    qs += __shfl_xor(qs, 1, 8);
    qs += __shfl_xor(qs, 2, 8);
    qs += __shfl_xor(qs, 4, 8);
    {
        float nm = fmaxf(mr, qs);
        float ex = __expf(qs - nm);
        if (nm > mr) {
            float sc = __expf(mr - nm);
            den *= sc;
            #pragma unroll
            for (int j = 0; j < 4; ++j) n[j] *= sc;
            mr = nm;
        }
        den += ex;
        #pragma unroll
        for (int j = 0; j < 4; ++j) n[j] = fmaf(ex, xs[j], n[j]);
    }
    float inv = 1.0f / (den + 1e-16f);
    if (lane == 0) wout[EE + v] = __expf(qs - mr) * inv;
    // normalize this node's edge weights (same-thread read-after-write)
    if (l == 0) {
        for (int k = sub; k < dg; k += 8) {
            int ide = eid[st + k];
            float q = wout[ide];
            wout[ide] = __expf(q - mr) * inv;
        }
    }
    if (sub == 0) {
        float4 bb = *(const float4*)(b2 + c0);
        float b_[4] = {bb.x, bb.y, bb.z, bb.w};
        float4 r;
        float* rp = &r.x;
        #pragma unroll
        for (int j = 0; j < 4; ++j) {
            float o = n[j] * inv + b_[j];
            rp[j] = (o > 0.f) ? o : (__expf(o) - 1.0f);
        }
        *(float4*)(h3 + (size_t)v * 32 + c0) = r;
    }
}

// ---------------------------------------------------------------- heads
__global__ __launch_bounds__(256) void k_head(const float* __restrict__ h3,
                                              const float* __restrict__ fc1W,
                                              const float* __restrict__ fc1b,
                                              const float* __restrict__ Wc,
                                              const float* __restrict__ bc,
                                              const float* __restrict__ Wt,
                                              const float* __restrict__ bt,
                                              float* __restrict__ outp) {
    __shared__ float sW1[32 * 32];
    __shared__ float sWc[32 * NCLONE];
    __shared__ float sWt[32 * NTYPE];
    __shared__ float sb1[32], sbc[NCLONE], sbt[NTYPE];
    int tid = threadIdx.x;
    for (int i = tid; i < 1024; i += 256) sW1[i] = fc1W[i];
    for (int i = tid; i < 32 * NCLONE; i += 256) sWc[i] = Wc[i];
    for (int i = tid; i < 32 * NTYPE; i += 256) sWt[i] = Wt[i];
    if (tid < 32) sb1[tid] = fc1b[tid];
    if (tid < NCLONE) sbc[tid] = bc[tid];
    if (tid < NTYPE) sbt[tid] = bt[tid];
    __syncthreads();
    int g = tid >> 5, l = tid & 31;
    int v = blockIdx.x * 8 + g;
    if (v >= NN) return;
    float x = h3[(size_t)v * CCH + l];
    float acc = sb1[l];
    #pragma unroll
    for (int c = 0; c < 32; ++c) {
        float xc = __shfl(x, c, 32);
        acc += xc * sW1[c * 32 + l];
    }
    float hl = fmaxf(acc, 0.0f);
    float at = (l < NTYPE) ? sbt[l] : 0.0f;
    float ac = (l < NCLONE) ? sbc[l] : 0.0f;
    #pragma unroll
    for (int c = 0; c < 32; ++c) {
        float hc = __shfl(hl, c, 32);
        float wt_ = (l < NTYPE) ? sWt[c * NTYPE + l] : 0.0f;
        float wc_ = (l < NCLONE) ? sWc[c * NCLONE + l] : 0.0f;
        at += hc * wt_;
        ac += hc * wc_;
    }
    float vt = (l < NTYPE) ? at : -INFINITY;
    float mt = vt;
    mt = fmaxf(mt, __shfl_xor(mt, 16, 32));
    mt = fmaxf(mt, __shfl_xor(mt, 8, 32));
    mt = fmaxf(mt, __shfl_xor(mt, 4, 32));
    mt = fmaxf(mt, __shfl_xor(mt, 2, 32));
    mt = fmaxf(mt, __shfl_xor(mt, 1, 32));
    float et = __expf(vt - mt);
    float stt = et;
    stt += __shfl_xor(stt, 16, 32);
    stt += __shfl_xor(stt, 8, 32);
    stt += __shfl_xor(stt, 4, 32);
    stt += __shfl_xor(stt, 2, 32);
    stt += __shfl_xor(stt, 1, 32);
    float lt = vt - mt - logf(stt);
    float vc = (l < NCLONE) ? ac : -INFINITY;
    float mc = vc;
    mc = fmaxf(mc, __shfl_xor(mc, 16, 32));
    mc = fmaxf(mc, __shfl_xor(mc, 8, 32));
    mc = fmaxf(mc, __shfl_xor(mc, 4, 32));
    mc = fmaxf(mc, __shfl_xor(mc, 2, 32));
    mc = fmaxf(mc, __shfl_xor(mc, 1, 32));
    float ec = __expf(vc - mc);
    float sc = ec;
    sc += __shfl_xor(sc, 16, 32);
    sc += __shfl_xor(sc, 8, 32);
    sc += __shfl_xor(sc, 4, 32);
    sc += __shfl_xor(sc, 2, 32);
    sc += __shfl_xor(sc, 1, 32);
    float lc = vc - mc - logf(sc);
    size_t ob = (size_t)v * 48;
    if (l < NCLONE) outp[ob + l] = lc;
    if (l < NTYPE) outp[ob + NCLONE + l] = lt;
}

// ---------------------------------------------------------------- launcher
extern "C" void kernel_launch(void* const* d_in, const int* in_sizes, int n_in,
                              void* d_out, int out_size, void* d_ws, size_t ws_size,
                              hipStream_t stream) {
    const float* x     = (const float*)d_in[0];
    const int*   ei    = (const int*)d_in[1];
    const float* ea    = (const float*)d_in[2];
    const float* Wl1   = (const float*)d_in[3];
    const float* Wr1   = (const float*)d_in[4];
    const float* We1   = (const float*)d_in[5];
    const float* att1  = (const float*)d_in[6];
    const float* b1    = (const float*)d_in[7];
    const float* skipW = (const float*)d_in[8];
    const float* skipb = (const float*)d_in[9];
    const float* bng   = (const float*)d_in[10];
    const float* bnb   = (const float*)d_in[11];
    const float* Wl2   = (const float*)d_in[12];
    const float* Wr2   = (const float*)d_in[13];
    const float* We2   = (const float*)d_in[14];
    const float* att2  = (const float*)d_in[15];
    const float* b2    = (const float*)d_in[16];
    const float* fc1W  = (const float*)d_in[17];
    const float* fc1b  = (const float*)d_in[18];
    const float* Wc    = (const float*)d_in[19];
    const float* bc    = (const float*)d_in[20];
    const float* Wt    = (const float*)d_in[21];
    const float* bt    = (const float*)d_in[22];
    float* out = (float*)d_out;
    float* wout = out + (size_t)NN * 48;

    const size_t NF = (size_t)NN * FIN;   // 12.8M elems
    char* w = (char*)d_ws;
    bf16_t* xl1b = (bf16_t*)w;  w += NF * 2;
    bf16_t* xr1b = (bf16_t*)w;  w += NF * 2;
    bf16_t* skb  = (bf16_t*)w;  w += NF * 2;
    bf16_t* hb   = (bf16_t*)w;  w += NF * 2;
    int2*   ep8  = (int2*)w;    w += (size_t)EE * 8;
    int*    eid  = (int*)w;     w += (size_t)EE * 4;
    int*    slot = (int*)w;     w += (size_t)EE * 4;
    int* deg   = (int*)w;   w += (size_t)NN * 4;
    int* offs  = (int*)w;   w += (size_t)NN * 4;
    float* mattr = (float*)w; w += (size_t)NN * 4;
    int*   bsum  = (int*)w;   w += 64 * 4;
    float* bns   = (float*)w; w += 128 * 4;
    float* bnq   = (float*)w; w += 128 * 4;
    float* scl   = (float*)w; w += 128 * 4;
    float* shf   = (float*)w; w += 128 * 4;
    bf16_t* WbT  = (bf16_t*)w; w += 384 * 128 * 2;
    bf16_t* Wb2T = (bf16_t*)w; w += 64 * 128 * 2;
    // aliases into dead regions (after gat1):
    bf16_t* xl2b = xl1b;              // 6.4 MB
    float*  xr2  = (float*)xr1b;      // 12.8 MB
    float*  h3   = (float*)skb;       // 12.8 MB

    hipMemsetAsync(deg, 0, (size_t)NN * sizeof(int), stream);
    hipMemsetAsync(bns, 0, 256 * sizeof(float), stream);   // bns + bnq

    k_wcvt<<<224, 256, 0, stream>>>(Wl1, Wr1, skipW, Wl2, Wr2, WbT, Wb2T);

    k_deg<<<6250, 256, 0, stream>>>(ei, deg, slot);
    k_scan1<<<SCAN_B, 256, 0, stream>>>(deg, offs, bsum);
    k_scan2<<<1, 64, 0, stream>>>(bsum);
    k_scan3<<<391, 256, 0, stream>>>(offs, bsum);
    k_fill<<<6250, 256, 0, stream>>>(ei, ea, offs, slot, ep8, eid);

    k_gemm1<<<dim3(782, 3), 256, 0, stream>>>(x, WbT, xl1b, xr1b, skb);
    k_gat1<<<25000, 256, 0, stream>>>(xl1b, xr1b, skb, offs, deg, ep8,
                                      att1, We1, b1, skipb, hb, mattr);
    k_bnstats<<<128, 256, 0, stream>>>(hb, bns, bnq);
    k_bnfinal<<<1, 128, 0, stream>>>(bns, bnq, bng, bnb, scl, shf);
    k_gemm2<<<782, 256, 0, stream>>>(hb, scl, shf, Wb2T, xl2b, xr2);
    k_gat2<<<25000, 256, 0, stream>>>(xl2b, xr2, mattr, offs, deg, ep8, eid,
                                      att2, We2, b2, h3, wout);
    k_head<<<12500, 256, 0, stream>>>(h3, fc1W, fc1b, Wc, bc, Wt, bt, out);
}

// Round 6
// 448.814 us; speedup vs baseline: 2.4026x; 1.0806x over previous
//
#include <hip/hip_runtime.h>
#include <math.h>

// Problem constants
#define NN 100000
#define EE 1600000
#define FIN 128
#define HCH 128     // H*C for gat1
#define CCH 32      // C
#define NCLONE 19
#define NTYPE 29
#define ETOT (EE + NN)
#define SCAN_B 49   // ceil(NN / 2048)

typedef __bf16 bf16_t;
typedef bf16_t bf16x2 __attribute__((ext_vector_type(2)));
typedef bf16_t bf16x4 __attribute__((ext_vector_type(4)));
typedef bf16_t bf16x8 __attribute__((ext_vector_type(8)));
typedef float f32x4 __attribute__((ext_vector_type(4)));

// ---------------------------------------------------------------- weight conversion
// WbT[n][k] (384x128), Wb2T[n][k] (64x128)
__global__ __launch_bounds__(256) void k_wcvt(const float* __restrict__ Wl1,
                                              const float* __restrict__ Wr1,
                                              const float* __restrict__ Ws,
                                              const float* __restrict__ Wl2,
                                              const float* __restrict__ Wr2,
                                              bf16_t* __restrict__ WbT,
                                              bf16_t* __restrict__ Wb2T) {
    int t = blockIdx.x * 256 + threadIdx.x;
    if (t < 384 * 128) {
        int n = t >> 7, k = t & 127;
        const float* W = (n < 128) ? Wl1 : ((n < 256) ? Wr1 : Ws);
        WbT[t] = (bf16_t)W[k * 128 + (n & 127)];
    } else if (t < 384 * 128 + 64 * 128) {
        int u = t - 384 * 128;
        int n = u >> 7, k = u & 127;
        const float* W = (n < 32) ? Wl2 : Wr2;
        Wb2T[u] = (bf16_t)W[k * 32 + (n & 31)];
    }
}

// ---------------------------------------------------------------- degree + slot
__global__ __launch_bounds__(256) void k_deg(const int* __restrict__ ei,
                                             int* __restrict__ deg,
                                             int* __restrict__ slot) {
    int e = blockIdx.x * 256 + threadIdx.x;
    if (e < EE) {
        int d = ei[EE + e];
        slot[e] = atomicAdd(&deg[d], 1);
    }
}

// ---------------------------------------------------------------- exclusive scan of deg
__global__ __launch_bounds__(256) void k_scan1(const int* __restrict__ deg,
                                               int* __restrict__ offs,
                                               int* __restrict__ bsum) {
    __shared__ int tsum[256];
    int b = blockIdx.x, tid = threadIdx.x;
    int base = b * 2048;
    int loc[8];
    int s = 0;
    #pragma unroll
    for (int i = 0; i < 8; ++i) {
        int idx = base + tid * 8 + i;
        int d = (idx < NN) ? deg[idx] : 0;
        loc[i] = s; s += d;
    }
    tsum[tid] = s;
    __syncthreads();
    for (int off = 1; off < 256; off <<= 1) {
        int v = (tid >= off) ? tsum[tid - off] : 0;
        __syncthreads();
        tsum[tid] += v;
        __syncthreads();
    }
    int texcl = tsum[tid] - s;
    #pragma unroll
    for (int i = 0; i < 8; ++i) {
        int idx = base + tid * 8 + i;
        if (idx < NN) offs[idx] = texcl + loc[i];
    }
    if (tid == 255) bsum[b] = tsum[255];
}

__global__ void k_scan2(int* __restrict__ bsum) {
    if (threadIdx.x == 0) {
        int run = 0;
        for (int i = 0; i < SCAN_B; ++i) { int t = bsum[i]; bsum[i] = run; run += t; }
    }
}

__global__ __launch_bounds__(256) void k_scan3(int* __restrict__ offs,
                                               const int* __restrict__ bsum) {
    int i = blockIdx.x * 256 + threadIdx.x;
    if (i < NN) offs[i] += bsum[i >> 11];
}

// ---------------------------------------------------------------- CSR fill (atomic-free)
__global__ __launch_bounds__(256) void k_fill(const int* __restrict__ ei,
                                              const float* __restrict__ ea,
                                              const int* __restrict__ offs,
                                              const int* __restrict__ slot,
                                              int2* __restrict__ ep8) {
    int e = blockIdx.x * 256 + threadIdx.x;
    if (e < EE) {
        int d = ei[EE + e];
        int pos = offs[d] + slot[e];
        ep8[pos] = make_int2(ei[e], __float_as_int(ea[e]));
    }
}

// ---------------------------------------------------------------- GEMM1 (MFMA): x(f32) @ WbT^T -> [xl1|xr1|skb]
// BM=128, K=128; A staged once, 3 column-chunks of 128 looped in-block.
__global__ __launch_bounds__(256) void k_gemm1(const float* __restrict__ x,
                                               const bf16_t* __restrict__ WbT,
                                               bf16_t* __restrict__ xl,
                                               bf16_t* __restrict__ xr,
                                               bf16_t* __restrict__ sk) {
    __shared__ bf16_t As[128 * 128];
    __shared__ bf16_t Bs[128 * 128];
    const int tid = threadIdx.x;
    const int row0 = blockIdx.x * 128;
    #pragma unroll
    for (int i = 0; i < 8; ++i) {
        int c = i * 256 + tid;
        int r = c >> 4, g = c & 15;
        int gr = row0 + r;
        bf16x8 v = {};
        if (gr < NN) {
            float4 f0 = *(const float4*)(x + (size_t)gr * 128 + g * 8);
            float4 f1 = *(const float4*)(x + (size_t)gr * 128 + g * 8 + 4);
            v[0] = (bf16_t)f0.x; v[1] = (bf16_t)f0.y; v[2] = (bf16_t)f0.z; v[3] = (bf16_t)f0.w;
            v[4] = (bf16_t)f1.x; v[5] = (bf16_t)f1.y; v[6] = (bf16_t)f1.z; v[7] = (bf16_t)f1.w;
        }
        *(bf16x8*)&As[r * 128 + ((g ^ (r & 7)) * 8)] = v;
    }

    const int wid = tid >> 6, lane = tid & 63;
    const int wm = wid >> 1, wn = wid & 1;
    const int lr = lane & 15, lg = lane >> 4;

    for (int chunk = 0; chunk < 3; ++chunk) {
        const int col0 = chunk * 128;
        bf16_t* __restrict__ out = (chunk == 0) ? xl : ((chunk == 1) ? xr : sk);
        __syncthreads();   // As ready (iter 0) / previous compute done
        #pragma unroll
        for (int i = 0; i < 8; ++i) {
            int c = i * 256 + tid;
            int n = c >> 4, g = c & 15;
            bf16x8 v = *(const bf16x8*)(WbT + (size_t)(col0 + n) * 128 + g * 8);
            *(bf16x8*)&Bs[n * 128 + ((g ^ (n & 7)) * 8)] = v;
        }
        __syncthreads();

        f32x4 acc[4][4] = {};
        #pragma unroll
        for (int ks = 0; ks < 4; ++ks) {
            int g = ks * 4 + lg;
            bf16x8 b[4];
            #pragma unroll
            for (int ni = 0; ni < 4; ++ni) {
                int n = wn * 64 + ni * 16 + lr;
                b[ni] = *(const bf16x8*)&Bs[n * 128 + ((g ^ (n & 7)) * 8)];
            }
            #pragma unroll
            for (int mi = 0; mi < 4; ++mi) {
                int r = wm * 64 + mi * 16 + lr;
                bf16x8 a = *(const bf16x8*)&As[r * 128 + ((g ^ (r & 7)) * 8)];
                #pragma unroll
                for (int ni = 0; ni < 4; ++ni)
                    acc[mi][ni] = __builtin_amdgcn_mfma_f32_16x16x32_bf16(a, b[ni], acc[mi][ni], 0, 0, 0);
            }
        }
        #pragma unroll
        for (int mi = 0; mi < 4; ++mi)
            #pragma unroll
            for (int ni = 0; ni < 4; ++ni)
                #pragma unroll
                for (int j = 0; j < 4; ++j) {
                    int gr = row0 + wm * 64 + mi * 16 + lg * 4 + j;
                    if (gr >= NN) continue;
                    int n = wn * 64 + ni * 16 + lr;
                    out[(size_t)gr * 128 + n] = (bf16_t)acc[mi][ni][j];
                }
    }
}

// ---------------------------------------------------------------- GAT1: one wave per node
// 16 lanes x 8ch per edge; 4 subgroups; depth-3 pipeline; self-loop last (mean attr inline).
__global__ __launch_bounds__(256) void k_gat1(const bf16_t* __restrict__ xl1,
                                              const bf16_t* __restrict__ xr1,
                                              const bf16_t* __restrict__ skb,
                                              const int* __restrict__ offs,
                                              const int* __restrict__ deg,
                                              const int2* __restrict__ ep8,
                                              const float* __restrict__ att1,
                                              const float* __restrict__ we1,
                                              const float* __restrict__ b1,
                                              const float* __restrict__ skipb,
                                              bf16_t* __restrict__ hb,
                                              float* __restrict__ mattr) {
    int v = (blockIdx.x * 256 + threadIdx.x) >> 6;
    if (v >= NN) return;
    int lane = threadIdx.x & 63;
    int sub = lane >> 4;
    int l = lane & 15;
    int c0 = l * 8;
    float at[8], we[8], xr[8];
    {
        float4 t0 = *(const float4*)(att1 + c0);
        float4 t1 = *(const float4*)(att1 + c0 + 4);
        at[0] = t0.x; at[1] = t0.y; at[2] = t0.z; at[3] = t0.w;
        at[4] = t1.x; at[5] = t1.y; at[6] = t1.z; at[7] = t1.w;
        float4 w0 = *(const float4*)(we1 + c0);
        float4 w1 = *(const float4*)(we1 + c0 + 4);
        we[0] = w0.x; we[1] = w0.y; we[2] = w0.z; we[3] = w0.w;
        we[4] = w1.x; we[5] = w1.y; we[6] = w1.z; we[7] = w1.w;
        bf16x8 xrv = *(const bf16x8*)(xr1 + (size_t)v * 128 + c0);
        #pragma unroll
        for (int j = 0; j < 8; ++j) xr[j] = (float)xrv[j];
    }
    float mr = -1e30f, den = 0.f, easum = 0.f;
    float n[8] = {};
    int st = offs[v], dg = deg[v];
    int i = sub;
    int2 e0 = make_int2(0, 0), e1 = make_int2(0, 0), e2 = make_int2(0, 0);
    bf16x8 a0 = {}, a1 = {};
    if (i < dg) e0 = ep8[st + i];
    if (i + 4 < dg) e1 = ep8[st + i + 4];
    if (i + 8 < dg) e2 = ep8[st + i + 8];
    if (i < dg) a0 = *(const bf16x8*)(xl1 + (size_t)e0.x * 128 + c0);
    if (i + 4 < dg) a1 = *(const bf16x8*)(xl1 + (size_t)e1.x * 128 + c0);
    for (; i < dg; i += 4) {
        bf16x8 a2 = {};
        int2 e3 = make_int2(0, 0);
        if (i + 8 < dg) a2 = *(const bf16x8*)(xl1 + (size_t)e2.x * 128 + c0);
        if (i + 12 < dg) e3 = ep8[st + i + 12];
        float ea_ = __int_as_float(e0.y);
        easum += ea_;
        float q = 0.f, xv[8];
        #pragma unroll
        for (int j = 0; j < 8; ++j) {
            xv[j] = (float)a0[j];
            float w_ = xv[j] + fmaf(ea_, we[j], xr[j]);
            w_ = (w_ > 0.f) ? w_ : 0.2f * w_;
            q = fmaf(w_, at[j], q);
        }
        q += __shfl_xor(q, 1, 4);
        q += __shfl_xor(q, 2, 4);
        float nm = fmaxf(mr, q);
        float ex = __expf(q - nm);
        if (nm > mr) {
            float sc = __expf(mr - nm);
            den *= sc;
            #pragma unroll
            for (int j = 0; j < 8; ++j) n[j] *= sc;
            mr = nm;
        }
        den += ex;
        #pragma unroll
        for (int j = 0; j < 8; ++j) n[j] = fmaf(ex, xv[j], n[j]);
        e0 = e1; e1 = e2; e2 = e3; a0 = a1; a1 = a2;
    }
    // merge 4 subgroup states
    #pragma unroll
    for (int w_ = 16; w_ <= 32; w_ <<= 1) {
        float mo = __shfl_xor(mr, w_, 64);
        float dn = __shfl_xor(den, w_, 64);
        float es = __shfl_xor(easum, w_, 64);
        float o[8];
        #pragma unroll
        for (int j = 0; j < 8; ++j) o[j] = __shfl_xor(n[j], w_, 64);
        float M = fmaxf(mr, mo);
        float sa = __expf(mr - M), sb = __expf(mo - M);
        den = den * sa + dn * sb;
        #pragma unroll
        for (int j = 0; j < 8; ++j) n[j] = n[j] * sa + o[j] * sb;
        mr = M;
        easum += es;
    }
    // self loop (mean edge attr)
    float eav = easum / fmaxf((float)dg, 1.0f);
    if (lane == 0) mattr[v] = eav;
    bf16x8 svv = *(const bf16x8*)(xl1 + (size_t)v * 128 + c0);
    float qs = 0.f, xs[8];
    #pragma unroll
    for (int j = 0; j < 8; ++j) {
        xs[j] = (float)svv[j];
        float w_ = xs[j] + fmaf(eav, we[j], xr[j]);
        w_ = (w_ > 0.f) ? w_ : 0.2f * w_;
        qs = fmaf(w_, at[j], qs);
    }
    qs += __shfl_xor(qs, 1, 4);
    qs += __shfl_xor(qs, 2, 4);
    {
        float nm = fmaxf(mr, qs);
        float ex = __expf(qs - nm);
        if (nm > mr) {
            float sc = __expf(mr - nm);
            den *= sc;
            #pragma unroll
            for (int j = 0; j < 8; ++j) n[j] *= sc;
            mr = nm;
        }
        den += ex;
        #pragma unroll
        for (int j = 0; j < 8; ++j) n[j] = fmaf(ex, xs[j], n[j]);
    }
    if (sub == 0) {
        float inv = 1.0f / (den + 1e-16f);
        float4 bb0 = *(const float4*)(b1 + c0);
        float4 bb1 = *(const float4*)(b1 + c0 + 4);
        float4 sb0 = *(const float4*)(skipb + c0);
        float4 sb1 = *(const float4*)(skipb + c0 + 4);
        bf16x8 skv = *(const bf16x8*)(skb + (size_t)v * 128 + c0);
        float bb[8] = {bb0.x, bb0.y, bb0.z, bb0.w, bb1.x, bb1.y, bb1.z, bb1.w};
        float sv[8] = {sb0.x, sb0.y, sb0.z, sb0.w, sb1.x, sb1.y, sb1.z, sb1.w};
        bf16x8 r;
        #pragma unroll
        for (int j = 0; j < 8; ++j)
            r[j] = (bf16_t)(n[j] * inv + bb[j] + (float)skv[j] + sv[j]);
        *(bf16x8*)(hb + (size_t)v * 128 + c0) = r;
    }
}

// ---------------------------------------------------------------- batchnorm stats (bf16 input, per-block LDS reduce)
__global__ __launch_bounds__(256) void k_bnstats(const bf16_t* __restrict__ h,
                                                 float* __restrict__ bns,
                                                 float* __restrict__ bnq) {
    __shared__ float sS[16 * 128];
    __shared__ float sQ[16 * 128];
    int tid = threadIdx.x;
    int cg = tid & 15;
    int slot = tid >> 4;
    int c0 = cg * 8;
    float s[8] = {}, q[8] = {};
    for (int r = blockIdx.x * 16 + slot; r < NN; r += gridDim.x * 16) {
        bf16x8 v = *(const bf16x8*)&h[(size_t)r * 128 + c0];
        #pragma unroll
        for (int j = 0; j < 8; ++j) { float f = (float)v[j]; s[j] += f; q[j] += f * f; }
    }
    #pragma unroll
    for (int j = 0; j < 8; ++j) { sS[slot * 128 + c0 + j] = s[j]; sQ[slot * 128 + c0 + j] = q[j]; }
    __syncthreads();
    if (tid < 128) {
        float as = 0.f, aq = 0.f;
        #pragma unroll
        for (int k = 0; k < 16; ++k) { as += sS[k * 128 + tid]; aq += sQ[k * 128 + tid]; }
        atomicAdd(&bns[tid], as);
        atomicAdd(&bnq[tid], aq);
    }
}

__global__ void k_bnfinal(const float* __restrict__ bns, const float* __restrict__ bnq,
                          const float* __restrict__ g, const float* __restrict__ b,
                          float* __restrict__ scale, float* __restrict__ shift) {
    int c = threadIdx.x;
    if (c < 128) {
        float mu = bns[c] * (1.0f / NN);
        float var = bnq[c] * (1.0f / NN) - mu * mu;
        float rs = rsqrtf(var + 1e-5f);
        float a = rs * g[c];
        scale[c] = a;
        shift[c] = b[c] - mu * a;
    }
}

// ---------------------------------------------------------------- GEMM2 (MFMA): elu(bn(h_bf16)) @ Wb2T^T -> [xl2 bf16 | xr2 f32]
__global__ __launch_bounds__(256) void k_gemm2(const bf16_t* __restrict__ h,
                                               const float* __restrict__ scl,
                                               const float* __restrict__ shf,
                                               const bf16_t* __restrict__ Wb2T,
                                               bf16_t* __restrict__ xl2,
                                               float* __restrict__ xr2) {
    __shared__ bf16_t As[128 * 128];
    __shared__ bf16_t Bs[64 * 128];
    const int tid = threadIdx.x;
    const int row0 = blockIdx.x * 128;
    #pragma unroll
    for (int i = 0; i < 8; ++i) {
        int c = i * 256 + tid;
        int r = c >> 4, g = c & 15;
        int gr = row0 + r;
        bf16x8 v = {};
        if (gr < NN) {
            bf16x8 hv = *(const bf16x8*)(h + (size_t)gr * 128 + g * 8);
            float4 s0 = *(const float4*)(scl + g * 8);
            float4 s1 = *(const float4*)(scl + g * 8 + 4);
            float4 t0 = *(const float4*)(shf + g * 8);
            float4 t1 = *(const float4*)(shf + g * 8 + 4);
            float e[8];
            e[0] = (float)hv[0] * s0.x + t0.x; e[1] = (float)hv[1] * s0.y + t0.y;
            e[2] = (float)hv[2] * s0.z + t0.z; e[3] = (float)hv[3] * s0.w + t0.w;
            e[4] = (float)hv[4] * s1.x + t1.x; e[5] = (float)hv[5] * s1.y + t1.y;
            e[6] = (float)hv[6] * s1.z + t1.z; e[7] = (float)hv[7] * s1.w + t1.w;
            #pragma unroll
            for (int j = 0; j < 8; ++j) {
                float vv = e[j];
                vv = (vv > 0.f) ? vv : (__expf(vv) - 1.0f);
                v[j] = (bf16_t)vv;
            }
        }
        *(bf16x8*)&As[r * 128 + ((g ^ (r & 7)) * 8)] = v;
    }
    #pragma unroll
    for (int i = 0; i < 4; ++i) {
        int c = i * 256 + tid;
        int n = c >> 4, g = c & 15;
        bf16x8 v = *(const bf16x8*)(Wb2T + (size_t)n * 128 + g * 8);
        *(bf16x8*)&Bs[n * 128 + ((g ^ (n & 7)) * 8)] = v;
    }
    __syncthreads();

    const int wid = tid >> 6, lane = tid & 63;
    const int wm = wid >> 1, wn = wid & 1;
    const int lr = lane & 15, lg = lane >> 4;
    f32x4 acc[4][2] = {};
    #pragma unroll
    for (int ks = 0; ks < 4; ++ks) {
        int g = ks * 4 + lg;
        bf16x8 b0, b1;
        {
            int n = wn * 32 + lr;
            b0 = *(const bf16x8*)&Bs[n * 128 + ((g ^ (n & 7)) * 8)];
            n += 16;
            b1 = *(const bf16x8*)&Bs[n * 128 + ((g ^ (n & 7)) * 8)];
        }
        #pragma unroll
        for (int mi = 0; mi < 4; ++mi) {
            int r = wm * 64 + mi * 16 + lr;
            bf16x8 a = *(const bf16x8*)&As[r * 128 + ((g ^ (r & 7)) * 8)];
            acc[mi][0] = __builtin_amdgcn_mfma_f32_16x16x32_bf16(a, b0, acc[mi][0], 0, 0, 0);
            acc[mi][1] = __builtin_amdgcn_mfma_f32_16x16x32_bf16(a, b1, acc[mi][1], 0, 0, 0);
        }
    }
    #pragma unroll
    for (int mi = 0; mi < 4; ++mi)
        #pragma unroll
        for (int ni = 0; ni < 2; ++ni)
            #pragma unroll
            for (int j = 0; j < 4; ++j) {
                int gr = row0 + wm * 64 + mi * 16 + lg * 4 + j;
                if (gr >= NN) continue;
                int n = wn * 32 + ni * 16 + lr;
                float val = acc[mi][ni][j];
                if (n < 32) xl2[(size_t)gr * 32 + n] = (bf16_t)val;
                else xr2[(size_t)gr * 32 + (n - 32)] = val;
            }
}

// ---------------------------------------------------------------- GAT2: one wave per node, 8 subgroups, depth-3; CSR-order alpha out
__global__ __launch_bounds__(256) void k_gat2(const bf16_t* __restrict__ xl2,
                                              const float* __restrict__ xr2,
                                              const float* __restrict__ mattr,
                                              const int* __restrict__ offs,
                                              const int* __restrict__ deg,
                                              const int2* __restrict__ ep8,
                                              const float* __restrict__ att2,
                                              const float* __restrict__ we2,
                                              const float* __restrict__ b2,
                                              float* __restrict__ h3,
                                              float* __restrict__ acsr,
                                              float2* __restrict__ MInv,
                                              float* __restrict__ wout) {
    int v = (blockIdx.x * 256 + threadIdx.x) >> 6;
    if (v >= NN) return;
    int lane = threadIdx.x & 63;
    int sub = lane >> 3;
    int l = lane & 7;
    int c0 = l * 4;
    float4 atv = *(const float4*)(att2 + c0);
    float4 wev = *(const float4*)(we2 + c0);
    float4 xrv = *(const float4*)(xr2 + (size_t)v * 32 + c0);
    float at[4] = {atv.x, atv.y, atv.z, atv.w};
    float we[4] = {wev.x, wev.y, wev.z, wev.w};
    float xr[4] = {xrv.x, xrv.y, xrv.z, xrv.w};
    float mr = -1e30f, den = 0.f;
    float n[4] = {};
    int st = offs[v], dg = deg[v];
    int i = sub;
    int2 e0 = make_int2(0, 0), e1 = make_int2(0, 0), e2 = make_int2(0, 0);
    bf16x4 a0 = {}, a1 = {};
    if (i < dg) e0 = ep8[st + i];
    if (i + 8 < dg) e1 = ep8[st + i + 8];
    if (i + 16 < dg) e2 = ep8[st + i + 16];
    if (i < dg) a0 = *(const bf16x4*)(xl2 + (size_t)e0.x * 32 + c0);
    if (i + 8 < dg) a1 = *(const bf16x4*)(xl2 + (size_t)e1.x * 32 + c0);
    for (; i < dg; i += 8) {
        bf16x4 a2 = {};
        int2 e3 = make_int2(0, 0);
        if (i + 16 < dg) a2 = *(const bf16x4*)(xl2 + (size_t)e2.x * 32 + c0);
        if (i + 24 < dg) e3 = ep8[st + i + 24];
        float ea_ = __int_as_float(e0.y);
        float q = 0.f, xv[4];
        #pragma unroll
        for (int j = 0; j < 4; ++j) {
            xv[j] = (float)a0[j];
            float w_ = xv[j] + fmaf(ea_, we[j], xr[j]);
            w_ = (w_ > 0.f) ? w_ : 0.2f * w_;
            q = fmaf(w_, at[j], q);
        }
        q += __shfl_xor(q, 1, 8);
        q += __shfl_xor(q, 2, 8);
        q += __shfl_xor(q, 4, 8);
        if (l == 0) acsr[st + i] = q;     // raw alpha, CSR order (coalesced-ish)
        float nm = fmaxf(mr, q);
        float ex = __expf(q - nm);
        if (nm > mr) {
            float sc = __expf(mr - nm);
            den *= sc;
            #pragma unroll
            for (int j = 0; j < 4; ++j) n[j] *= sc;
            mr = nm;
        }
        den += ex;
        #pragma unroll
        for (int j = 0; j < 4; ++j) n[j] = fmaf(ex, xv[j], n[j]);
        e0 = e1; e1 = e2; e2 = e3; a0 = a1; a1 = a2;
    }
    // merge 8 subgroup states
    #pragma unroll
    for (int w_ = 8; w_ <= 32; w_ <<= 1) {
        float mo = __shfl_xor(mr, w_, 64);
        float dn = __shfl_xor(den, w_, 64);
        float o[4];
        #pragma unroll
        for (int j = 0; j < 4; ++j) o[j] = __shfl_xor(n[j], w_, 64);
        float M = fmaxf(mr, mo);
        float sa = __expf(mr - M), sb = __expf(mo - M);
        den = den * sa + dn * sb;
        #pragma unroll
        for (int j = 0; j < 4; ++j) n[j] = n[j] * sa + o[j] * sb;
        mr = M;
    }
    // self loop
    float eav = mattr[v];
    bf16x4 sv = *(const bf16x4*)(xl2 + (size_t)v * 32 + c0);
    float qs = 0.f, xs[4];
    #pragma unroll
    for (int j = 0; j < 4; ++j) {
        xs[j] = (float)sv[j];
        float w_ = xs[j] + fmaf(eav, we[j], xr[j]);
        w_ = (w_ > 0.f) ? w_ : 0.2f * w_;
        qs = fmaf(w_, at[j], qs);
    }
    qs += __shfl_xor(qs, 1, 8);
    qs += __shfl_xor(qs, 2, 8);
    qs += __shfl_xor(qs, 4, 8);
    {
        float nm = fmaxf(mr, qs);
        float ex = __expf(qs - nm);
        if (nm > mr) {
            float sc = __expf(mr - nm);
            den *= sc;
            #pragma unroll
            for (int j = 0; j < 4; ++j) n[j] *= sc;
            mr = nm;
        }
        den += ex;
        #pragma unroll
        for (int j = 0; j < 4; ++j) n[j] = fmaf(ex, xs[j], n[j]);
    }
    float inv = 1.0f / (den + 1e-16f);
    if (lane == 0) {
        MInv[v] = make_float2(mr, inv);
        wout[EE + v] = __expf(qs - mr) * inv;
    }
    if (sub == 0) {
        float4 bb = *(const float4*)(b2 + c0);
        float b_[4] = {bb.x, bb.y, bb.z, bb.w};
        float4 r;
        float* rp = &r.x;
        #pragma unroll
        for (int j = 0; j < 4; ++j) {
            float o = n[j] * inv + b_[j];
            rp[j] = (o > 0.f) ? o : (__expf(o) - 1.0f);
        }
        *(float4*)(h3 + (size_t)v * 32 + c0) = r;
    }
}

// ---------------------------------------------------------------- finalize attention weights (original edge order, coalesced out)
__global__ __launch_bounds__(256) void k_wfinal(const int* __restrict__ ei,
                                                const int* __restrict__ offs,
                                                const int* __restrict__ slot,
                                                const float* __restrict__ acsr,
                                                const float2* __restrict__ MInv,
                                                float* __restrict__ wout) {
    int e = blockIdx.x * 256 + threadIdx.x;
    if (e >= EE) return;
    int d = ei[EE + e];
    float2 mi = MInv[d];
    float al = acsr[offs[d] + slot[e]];
    wout[e] = __expf(al - mi.x) * mi.y;
}

// ---------------------------------------------------------------- heads
__global__ __launch_bounds__(256) void k_head(const float* __restrict__ h3,
                                              const float* __restrict__ fc1W,
                                              const float* __restrict__ fc1b,
                                              const float* __restrict__ Wc,
                                              const float* __restrict__ bc,
                                              const float* __restrict__ Wt,
                                              const float* __restrict__ bt,
                                              float* __restrict__ outp) {
    __shared__ float sW1[32 * 32];
    __shared__ float sWc[32 * NCLONE];
    __shared__ float sWt[32 * NTYPE];
    __shared__ float sb1[32], sbc[NCLONE], sbt[NTYPE];
    int tid = threadIdx.x;
    for (int i = tid; i < 1024; i += 256) sW1[i] = fc1W[i];
    for (int i = tid; i < 32 * NCLONE; i += 256) sWc[i] = Wc[i];
    for (int i = tid; i < 32 * NTYPE; i += 256) sWt[i] = Wt[i];
    if (tid < 32) sb1[tid] = fc1b[tid];
    if (tid < NCLONE) sbc[tid] = bc[tid];
    if (tid < NTYPE) sbt[tid] = bt[tid];
    __syncthreads();
    int g = tid >> 5, l = tid & 31;
    int v = blockIdx.x * 8 + g;
    if (v >= NN) return;
    float x = h3[(size_t)v * CCH + l];
    float acc = sb1[l];
    #pragma unroll
    for (int c = 0; c < 32; ++c) {
        float xc = __shfl(x, c, 32);
        acc += xc * sW1[c * 32 + l];
    }
    float hl = fmaxf(acc, 0.0f);
    float at = (l < NTYPE) ? sbt[l] : 0.0f;
    float ac = (l < NCLONE) ? sbc[l] : 0.0f;
    #pragma unroll
    for (int c = 0; c < 32; ++c) {
        float hc = __shfl(hl, c, 32);
        float wt_ = (l < NTYPE) ? sWt[c * NTYPE + l] : 0.0f;
        float wc_ = (l < NCLONE) ? sWc[c * NCLONE + l] : 0.0f;
        at += hc * wt_;
        ac += hc * wc_;
    }
    float vt = (l < NTYPE) ? at : -INFINITY;
    float mt = vt;
    mt = fmaxf(mt, __shfl_xor(mt, 16, 32));
    mt = fmaxf(mt, __shfl_xor(mt, 8, 32));
    mt = fmaxf(mt, __shfl_xor(mt, 4, 32));
    mt = fmaxf(mt, __shfl_xor(mt, 2, 32));
    mt = fmaxf(mt, __shfl_xor(mt, 1, 32));
    float et = __expf(vt - mt);
    float stt = et;
    stt += __shfl_xor(stt, 16, 32);
    stt += __shfl_xor(stt, 8, 32);
    stt += __shfl_xor(stt, 4, 32);
    stt += __shfl_xor(stt, 2, 32);
    stt += __shfl_xor(stt, 1, 32);
    float lt = vt - mt - logf(stt);
    float vc = (l < NCLONE) ? ac : -INFINITY;
    float mc = vc;
    mc = fmaxf(mc, __shfl_xor(mc, 16, 32));
    mc = fmaxf(mc, __shfl_xor(mc, 8, 32));
    mc = fmaxf(mc, __shfl_xor(mc, 4, 32));
    mc = fmaxf(mc, __shfl_xor(mc, 2, 32));
    mc = fmaxf(mc, __shfl_xor(mc, 1, 32));
    float ec = __expf(vc - mc);
    float sc = ec;
    sc += __shfl_xor(sc, 16, 32);
    sc += __shfl_xor(sc, 8, 32);
    sc += __shfl_xor(sc, 4, 32);
    sc += __shfl_xor(sc, 2, 32);
    sc += __shfl_xor(sc, 1, 32);
    float lc = vc - mc - logf(sc);
    size_t ob = (size_t)v * 48;
    if (l < NCLONE) outp[ob + l] = lc;
    if (l < NTYPE) outp[ob + NCLONE + l] = lt;
}

// ---------------------------------------------------------------- launcher
extern "C" void kernel_launch(void* const* d_in, const int* in_sizes, int n_in,
                              void* d_out, int out_size, void* d_ws, size_t ws_size,
                              hipStream_t stream) {
    const float* x     = (const float*)d_in[0];
    const int*   ei    = (const int*)d_in[1];
    const float* ea    = (const float*)d_in[2];
    const float* Wl1   = (const float*)d_in[3];
    const float* Wr1   = (const float*)d_in[4];
    const float* We1   = (const float*)d_in[5];
    const float* att1  = (const float*)d_in[6];
    const float* b1    = (const float*)d_in[7];
    const float* skipW = (const float*)d_in[8];
    const float* skipb = (const float*)d_in[9];
    const float* bng   = (const float*)d_in[10];
    const float* bnb   = (const float*)d_in[11];
    const float* Wl2   = (const float*)d_in[12];
    const float* Wr2   = (const float*)d_in[13];
    const float* We2   = (const float*)d_in[14];
    const float* att2  = (const float*)d_in[15];
    const float* b2    = (const float*)d_in[16];
    const float* fc1W  = (const float*)d_in[17];
    const float* fc1b  = (const float*)d_in[18];
    const float* Wc    = (const float*)d_in[19];
    const float* bc    = (const float*)d_in[20];
    const float* Wt    = (const float*)d_in[21];
    const float* bt    = (const float*)d_in[22];
    float* out = (float*)d_out;
    float* wout = out + (size_t)NN * 48;

    const size_t NF = (size_t)NN * FIN;   // 12.8M elems
    char* w = (char*)d_ws;
    bf16_t* xl1b = (bf16_t*)w;  w += NF * 2;
    bf16_t* xr1b = (bf16_t*)w;  w += NF * 2;
    bf16_t* skb  = (bf16_t*)w;  w += NF * 2;
    bf16_t* hb   = (bf16_t*)w;  w += NF * 2;
    int2*   ep8  = (int2*)w;    w += (size_t)EE * 8;
    float*  acsr = (float*)w;   w += (size_t)EE * 4;
    int*    slot = (int*)w;     w += (size_t)EE * 4;
    int* deg   = (int*)w;   w += (size_t)NN * 4;
    int* offs  = (int*)w;   w += (size_t)NN * 4;
    float* mattr = (float*)w; w += (size_t)NN * 4;
    float2* MInv = (float2*)w; w += (size_t)NN * 8;
    int*   bsum  = (int*)w;   w += 64 * 4;
    float* bns   = (float*)w; w += 128 * 4;
    float* bnq   = (float*)w; w += 128 * 4;
    float* scl   = (float*)w; w += 128 * 4;
    float* shf   = (float*)w; w += 128 * 4;
    bf16_t* WbT  = (bf16_t*)w; w += 384 * 128 * 2;
    bf16_t* Wb2T = (bf16_t*)w; w += 64 * 128 * 2;
    // aliases into dead regions (after gat1):
    bf16_t* xl2b = xl1b;              // 6.4 MB
    float*  xr2  = (float*)xr1b;      // 12.8 MB
    float*  h3   = (float*)skb;       // 12.8 MB

    hipMemsetAsync(deg, 0, (size_t)NN * sizeof(int), stream);
    hipMemsetAsync(bns, 0, 256 * sizeof(float), stream);   // bns + bnq

    k_wcvt<<<224, 256, 0, stream>>>(Wl1, Wr1, skipW, Wl2, Wr2, WbT, Wb2T);

    k_deg<<<6250, 256, 0, stream>>>(ei, deg, slot);
    k_scan1<<<SCAN_B, 256, 0, stream>>>(deg, offs, bsum);
    k_scan2<<<1, 64, 0, stream>>>(bsum);
    k_scan3<<<391, 256, 0, stream>>>(offs, bsum);
    k_fill<<<6250, 256, 0, stream>>>(ei, ea, offs, slot, ep8);

    k_gemm1<<<782, 256, 0, stream>>>(x, WbT, xl1b, xr1b, skb);
    k_gat1<<<25000, 256, 0, stream>>>(xl1b, xr1b, skb, offs, deg, ep8,
                                      att1, We1, b1, skipb, hb, mattr);
    k_bnstats<<<128, 256, 0, stream>>>(hb, bns, bnq);
    k_bnfinal<<<1, 128, 0, stream>>>(bns, bnq, bng, bnb, scl, shf);
    k_gemm2<<<782, 256, 0, stream>>>(hb, scl, shf, Wb2T, xl2b, xr2);
    k_gat2<<<25000, 256, 0, stream>>>(xl2b, xr2, mattr, offs, deg, ep8,
                                      att2, We2, b2, h3, acsr, MInv, wout);
    k_wfinal<<<6250, 256, 0, stream>>>(ei, offs, slot, acsr, MInv, wout);
    k_head<<<12500, 256, 0, stream>>>(h3, fc1W, fc1b, Wc, bc, Wt, bt, out);
}